// Round 20
// baseline (646.890 us; speedup 1.0000x reference)
//
#include <hip/hip_runtime.h>
#include <hip/hip_fp16.h>

#define NN 100000      // nodes
#define NE 1600000     // edges
#define NF 128         // input features
#define H  64          // hidden channels
#define NG 4096        // graphs

#define NBK 512        // dst buckets
#define BKN 196        // nodes per bucket (512*196 >= NN)
#define CAP 4096       // edge capacity per bucket (avg 3125, sigma 56)
#define NBLK_BIN 256
#define CHUNK ((NE + NBLK_BIN - 1) / NBLK_BIN)   // 6250

typedef unsigned long long u64;
typedef unsigned int u32;
typedef __attribute__((ext_vector_type(2))) _Float16 h2;

__device__ inline u32 packh2(float x, float y) {
  __half2 h = __floats2half2_rn(x, y);
  return *reinterpret_cast<u32*>(&h);
}
__device__ inline float2 unpackh2(u32 u) {
  __half2 h = *reinterpret_cast<__half2*>(&u);
  return __half22float2(h);
}

#if __has_builtin(__builtin_amdgcn_fdot2)
__device__ inline float dot2(h2 a, h2 b, float c) {
  return __builtin_amdgcn_fdot2(a, b, c, false);
}
#else
__device__ inline float dot2(h2 a, h2 b, float c) {
  return fmaf((float)a.x, (float)b.x, fmaf((float)a.y, (float)b.y, c));
}
#endif

// ---- workspace zeroing (single cheap kernel; pool+pcnt contiguous) --------
__global__ __launch_bounds__(256) void k_zero(int* __restrict__ bcur,
                                              int* __restrict__ gcur,
                                              float4* __restrict__ poolv) {
  const int t = blockIdx.x * 256 + threadIdx.x;
  poolv[t] = make_float4(0.f, 0.f, 0.f, 0.f);
  if (t < NBK) bcur[t] = 0;
  if (t < 64) gcur[t] = 0;
}

// ---- phase 1: bucket-bin edges (u32 = dloc<<17 | src), block-local runs ----
// 256 blocks: per-(block,bucket) runs ~12 edges = 48 B -> low write amp.
__global__ __launch_bounds__(256) void k_bin(const int* __restrict__ src,
                                             const int* __restrict__ dst,
                                             int* __restrict__ bcur,
                                             u32* __restrict__ ebuf) {
  __shared__ int d_s[CHUNK];          // 25 KB: dst chunk staged once
  __shared__ int bcnt[NBK], bpos[NBK];
  const int e0 = blockIdx.x * CHUNK;
  const int e1 = min(e0 + CHUNK, NE);
  for (int i = threadIdx.x; i < NBK; i += 256) bcnt[i] = 0;
  __syncthreads();
  for (int e = e0 + threadIdx.x; e < e1; e += 256) {
    const int d = dst[e];
    d_s[e - e0] = d;
    atomicAdd(&bcnt[d / BKN], 1);
  }
  __syncthreads();
  for (int i = threadIdx.x; i < NBK; i += 256) {
    const int c = bcnt[i];
    if (c) bpos[i] = i * CAP + atomicAdd(&bcur[i], c);
  }
  __syncthreads();
  for (int e = e0 + threadIdx.x; e < e1; e += 256) {
    const int d = d_s[e - e0];
    const int bk = d / BKN;
    const int pos = atomicAdd(&bpos[bk], 1);
    ebuf[pos] = ((u32)(d - bk * BKN) << 17) | (u32)src[e];
  }
}

// ---- phase 2: per-bucket CSR build, src-octant-ordered adjacency ----------
// csr entries PRE-SCALED (src*16 = u64-row index of hw16).
// Bucket tail zero-padded so k_agg can over-read without clamping.
__global__ __launch_bounds__(256) void k_csr(const int* __restrict__ bcur,
                                             const u32* __restrict__ ebuf,
                                             int* __restrict__ row_ptr,
                                             int* __restrict__ cnt,
                                             float* __restrict__ dinv,
                                             int* __restrict__ csr_src) {
  __shared__ u32 eb_s[CAP];           // 16 KB
  __shared__ int deg[256], sc[256], cur[256];
  const int bk = blockIdx.x;
  const int nlo = bk * BKN;
  if (nlo >= NN) return;
  const int nloc = min(BKN, NN - nlo);
  const int cntE = bcur[bk];
  const int t = threadIdx.x;
  for (int e = t; e < cntE; e += 256) eb_s[e] = ebuf[(size_t)bk * CAP + e];
  deg[t] = 0;
  __syncthreads();
  for (int e = t; e < cntE; e += 256) atomicAdd(&deg[eb_s[e] >> 17], 1);
  __syncthreads();
  sc[t] = deg[t];
  __syncthreads();
  for (int off = 1; off < 256; off <<= 1) {
    const int add = (t >= off) ? sc[t - off] : 0;
    __syncthreads();
    sc[t] += add;
    __syncthreads();
  }
  const int excl = bk * CAP + sc[t] - deg[t];
  if (t < nloc) {
    row_ptr[nlo + t] = excl;
    cnt[nlo + t] = deg[t];
    dinv[nlo + t] = 1.0f / sqrtf((float)deg[t] + 1.0f);
  }
  cur[t] = excl;
  __syncthreads();
  for (int oct = 0; oct < 8; ++oct) {
    for (int e = t; e < cntE; e += 256) {
      const u32 ent = eb_s[e];
      const int s = (int)(ent & 0x1ffffu);
      if (((s >> 14) & 7) == oct) {
        const int pos = atomicAdd(&cur[ent >> 17], 1);
        csr_src[pos] = s << 4;  // pre-scaled (u64 units)
      }
    }
    __syncthreads();
  }
  // zero-pad tail so degree-mismatched groups can over-read safely
  for (int e = cntE + t; e < min(cntE + 64, CAP); e += 256)
    csr_src[bk * CAP + e] = 0;
}

// ---- degree counting sort: order[] groups nodes of equal/adjacent degree ---
__global__ __launch_bounds__(256) void k_obin(const int* __restrict__ cnt,
                                              int* __restrict__ gcur) {
  __shared__ int lh[64];
  const int t = threadIdx.x;
  if (t < 64) lh[t] = 0;
  __syncthreads();
  const int n = blockIdx.x * 256 + t;
  if (n < NN) atomicAdd(&lh[min(cnt[n], 63)], 1);
  __syncthreads();
  if (t < 64 && lh[t]) atomicAdd(&gcur[t], lh[t]);
}

__global__ __launch_bounds__(64) void k_oscan(int* __restrict__ gcur) {
  __shared__ int sh[64];
  const int t = threadIdx.x;
  const int v = gcur[t];
  sh[t] = v;
  __syncthreads();
  for (int off = 1; off < 64; off <<= 1) {
    const int a = (t >= off) ? sh[t - off] : 0;
    __syncthreads();
    sh[t] += a;
    __syncthreads();
  }
  gcur[t] = sh[t] - v;  // exclusive offset -> running cursor
}

__global__ __launch_bounds__(256) void k_oscat(const int* __restrict__ cnt,
                                               int* __restrict__ gcur,
                                               int* __restrict__ order) {
  __shared__ int lh[64], lo[64];
  const int t = threadIdx.x;
  if (t < 64) lh[t] = 0;
  __syncthreads();
  const int n = blockIdx.x * 256 + t;
  int bin = 0, loc = 0;
  if (n < NN) {
    bin = min(cnt[n], 63);
    loc = atomicAdd(&lh[bin], 1);
  }
  __syncthreads();
  if (t < 64 && lh[t]) lo[t] = atomicAdd(&gcur[t], lh[t]);
  __syncthreads();
  if (n < NN) order[lo[bin] + loc] = n;
}

// ---- node GEMM: fp16 + v_dot2_f32_f16, fp32 accumulate, K-CHUNKED ---------
// Block 256 threads = tile 128 rows x 64 cols; thread = 4 rows x 8 cols.
// tin2 staged in 64-float K-chunks ([128][36] h2 = 18.4 KB) -> total LDS
// ~36 KB -> 4 blocks/CU. Weights fully resident. A: TXOR swizzle;
// B: WIDX bank-quad offset. SK: skip result packed fp16 -> outS16.
#define TXOR(row) ((((row) >> 3) & 3) << 2)
#define WIDX(c, kp) ((c) * WS + (((c) >> 3) << 2) + (kp))
template <int CI, bool SK>
__global__ __launch_bounds__(256) void k_gemm(const float* __restrict__ in,
                                              const float* __restrict__ W,
                                              const float* __restrict__ Ws,
                                              const float* __restrict__ bs,
                                              const float* __restrict__ dinv,
                                              u32* __restrict__ out16,
                                              u32* __restrict__ outS16) {
  constexpr int KP = CI / 2;          // half2 per row (total)
  constexpr int KC = 32;              // half2 per K-chunk (64 floats)
  constexpr int NCH = KP / KC;        // 1 (CI=64) or 2 (CI=128)
  constexpr int RS = KC + 4;          // tin2 row stride = 36
  constexpr int WS = KP + 4;          // wt2 col stride (+ per-col quad offset)
  __shared__ h2 tin2[128 * RS];       // 18.4 KB
  __shared__ h2 wt2[64 * WS + 32];
  __shared__ h2 wsl2[SK ? 64 * WS + 32 : 1];
  union U2 { uint2 u; h2 h[2]; };
  union U4 { uint4 u; h2 h[4]; };

  const int row0 = blockIdx.x * 128;
  // stage weights (transposed, fp16) once
  for (int i = threadIdx.x; i < 64 * KP; i += 256) {
    const int c = i & 63;
    const int kp = i >> 6;
    wt2[WIDX(c, kp)] = h2{(_Float16)W[(2 * kp) * 64 + c],
                          (_Float16)W[(2 * kp + 1) * 64 + c]};
    if (SK)
      wsl2[WIDX(c, kp)] = h2{(_Float16)Ws[(2 * kp) * 64 + c],
                             (_Float16)Ws[(2 * kp + 1) * 64 + c]};
  }

  const int rg = threadIdx.x >> 3;  // 0..31: 4-row group
  const int cg = threadIdx.x & 7;   // 0..7 : 8-col group
  float acc[4][8];
  float sacc[SK ? 4 : 1][8];
#pragma unroll
  for (int i = 0; i < 4; ++i)
#pragma unroll
    for (int j = 0; j < 8; ++j) acc[i][j] = 0.0f;
  if (SK) {
#pragma unroll
    for (int i = 0; i < 4; ++i)
#pragma unroll
      for (int j = 0; j < 8; ++j) sacc[i][j] = bs[cg * 8 + j];
  }
  const int tx = TXOR(rg * 4);  // same for the thread's 4 rows

  for (int ch = 0; ch < NCH; ++ch) {
    __syncthreads();  // previous chunk consumed (and wt2 ready on ch==0... )
    // stage this K-chunk fp32->fp16: 128 rows x 64 floats = 8 float4/thread
#pragma unroll
    for (int s = 0; s < 8; ++s) {
      const int idx = (s * 256 + threadIdx.x) * 4;
      const int r = idx >> 6;           // /64
      const int k = idx & 63;           // chunk-local float idx
      const int rowc = min(row0 + r, NN - 1);
      const float4 v = *(const float4*)(in + (size_t)rowc * CI + ch * 64 + k);
      U2 a;
      a.h[0] = h2{(_Float16)v.x, (_Float16)v.y};
      a.h[1] = h2{(_Float16)v.z, (_Float16)v.w};
      const int kp = (k >> 1) ^ TXOR(r);  // xor quad bits (pair stays in-quad)
      *(uint2*)&tin2[r * RS + kp] = a.u;
    }
    __syncthreads();
#pragma unroll
    for (int kq = 0; kq < KC / 4; ++kq) {
      U4 A[4], B[8];
#pragma unroll
      for (int r = 0; r < 4; ++r)
        A[r].u = *(const uint4*)&tin2[(rg * 4 + r) * RS + ((kq * 4) ^ tx)];
#pragma unroll
      for (int c = 0; c < 8; ++c)
        B[c].u = *(const uint4*)&wt2[WIDX(cg * 8 + c, ch * KC + kq * 4)];
#pragma unroll
      for (int r = 0; r < 4; ++r)
#pragma unroll
        for (int c = 0; c < 8; ++c)
#pragma unroll
          for (int q = 0; q < 4; ++q)
            acc[r][c] = dot2(A[r].h[q], B[c].h[q], acc[r][c]);
      if (SK) {
        U4 C[8];
#pragma unroll
        for (int c = 0; c < 8; ++c)
          C[c].u = *(const uint4*)&wsl2[WIDX(cg * 8 + c, ch * KC + kq * 4)];
#pragma unroll
        for (int r = 0; r < 4; ++r)
#pragma unroll
          for (int c = 0; c < 8; ++c)
#pragma unroll
            for (int q = 0; q < 4; ++q)
              sacc[r][c] = dot2(A[r].h[q], C[c].h[q], sacc[r][c]);
      }
    }
  }

#pragma unroll
  for (int i = 0; i < 4; ++i) {
    const int row = row0 + rg * 4 + i;
    if (row < NN) {
      const float dv = dinv[row];
      u32 o[4];
#pragma unroll
      for (int j = 0; j < 4; ++j)
        o[j] = packh2(acc[i][2 * j] * dv, acc[i][2 * j + 1] * dv);
      *(uint4*)&out16[(size_t)row * 32 + cg * 4] =
          make_uint4(o[0], o[1], o[2], o[3]);
      if (SK) {
        u32 so[4];
#pragma unroll
        for (int j = 0; j < 4; ++j)
          so[j] = packh2(sacc[i][2 * j], sacc[i][2 * j + 1]);
        *(uint4*)&outS16[(size_t)row * 32 + cg * 4] =
            make_uint4(so[0], so[1], so[2], so[3]);
      }
    }
  }
}

// ------- CSR aggregation + finalize (fp16 gather, 2 quads = 8 nodes/wave) ---
// Wave = 4 nodes x 16 lanes x 2 independent streams (A,B); staggered gather
// sub-batches keep ~16 gathers in flight sustained. gid REVERSED so
// high-degree (long-pole) blocks launch first; short blocks backfill.
template <bool ADD_S>
__global__ __launch_bounds__(256) void k_agg(const u32* __restrict__ hw16,
                                             const u32* __restrict__ hs16,
                                             const int* __restrict__ csr_src,
                                             const int* __restrict__ row_ptr,
                                             const int* __restrict__ cnt,
                                             const float* __restrict__ dinv,
                                             const float* __restrict__ bias,
                                             const int* __restrict__ order,
                                             float* __restrict__ h) {
  const int lane = threadIdx.x & 63;
  const int grp  = lane >> 4;        // node within quad
  const int cl   = lane & 15;        // col-quad index (4 fp16 = 8 B)
  const int wv   = threadIdx.x >> 6;
  const int gid  = 12499 - (blockIdx.x * 4 + wv);  // high-degree first
  const int nA = order[(gid * 2) * 4 + grp];
  const int nB = order[(gid * 2 + 1) * 4 + grp];
  const int begA = row_ptr[nA], degA = cnt[nA];
  const int begB = row_ptr[nB], degB = cnt[nB];
  int d1 = max(degA, degB);
  d1 = max(d1, __shfl_xor(d1, 16));
  const int dmax = max(d1, __shfl_xor(d1, 32));
  const u64* hw64 = (const u64*)hw16;
  const int gbase = grp << 4;
  float4 accA = make_float4(0.f, 0.f, 0.f, 0.f);
  float4 accB = make_float4(0.f, 0.f, 0.f, 0.f);

#define GATH(dst, idxv, K0, NK)                                               \
  _Pragma("unroll") for (int k = 0; k < NK; ++k) {                            \
    const int p = __shfl(idxv, gbase + (K0) + k);                             \
    dst[k] = *(const uint2*)&hw64[(size_t)(p + cl)];                          \
  }
#define ACC(uv, accv, deg, K0, NK)                                            \
  _Pragma("unroll") for (int k = 0; k < NK; ++k) {                            \
    const float m = ((i + (K0) + k) < (deg)) ? 1.0f : 0.0f;                   \
    const float2 f0 = unpackh2(uv[k].x);                                      \
    const float2 f1 = unpackh2(uv[k].y);                                      \
    accv.x = fmaf(f0.x, m, accv.x);                                           \
    accv.y = fmaf(f0.y, m, accv.y);                                           \
    accv.z = fmaf(f1.x, m, accv.z);                                           \
    accv.w = fmaf(f1.y, m, accv.w);                                           \
  }

  int i = 0;
  while (i + 16 <= dmax) {
    const int ivA = __builtin_nontemporal_load(&csr_src[begA + i + cl]);
    const int ivB = __builtin_nontemporal_load(&csr_src[begB + i + cl]);
    uint2 a0[8], b0[8], a1[8], b1[8];
    GATH(a0, ivA, 0, 8)
    GATH(b0, ivB, 0, 8)
    ACC(a0, accA, degA, 0, 8)
    GATH(a1, ivA, 8, 8)
    ACC(b0, accB, degB, 0, 8)
    GATH(b1, ivB, 8, 8)
    ACC(a1, accA, degA, 8, 8)
    ACC(b1, accB, degB, 8, 8)
    i += 16;
  }
  if (i < dmax) {
    const int ivA = __builtin_nontemporal_load(&csr_src[begA + i + cl]);
    const int ivB = __builtin_nontemporal_load(&csr_src[begB + i + cl]);
    const int rem = dmax - i;  // wave-uniform, 1..15
    int k0 = 0;
    if (rem & 8) {
      uint2 a[8], b[8];
      GATH(a, ivA, k0, 8) GATH(b, ivB, k0, 8)
      ACC(a, accA, degA, k0, 8) ACC(b, accB, degB, k0, 8)
      k0 += 8;
    }
    if (rem & 4) {
      uint2 a[4], b[4];
      GATH(a, ivA, k0, 4) GATH(b, ivB, k0, 4)
      ACC(a, accA, degA, k0, 4) ACC(b, accB, degB, k0, 4)
      k0 += 4;
    }
    if (rem & 2) {
      uint2 a[2], b[2];
      GATH(a, ivA, k0, 2) GATH(b, ivB, k0, 2)
      ACC(a, accA, degA, k0, 2) ACC(b, accB, degB, k0, 2)
      k0 += 2;
    }
    if (rem & 1) {
      uint2 a[1], b[1];
      GATH(a, ivA, k0, 1) GATH(b, ivB, k0, 1)
      ACC(a, accA, degA, k0, 1) ACC(b, accB, degB, k0, 1)
    }
  }
#undef GATH
#undef ACC

#define FINAL(n, accv)                                                        \
  {                                                                           \
    const uint2 sv = *(const uint2*)&hw64[(size_t)(n) * 16 + cl];             \
    const float2 s0 = unpackh2(sv.x);                                         \
    const float2 s1 = unpackh2(sv.y);                                         \
    const float dv = dinv[n];                                                 \
    const float4 brc = *(const float4*)&bias[cl * 4];                         \
    float4 r;                                                                 \
    r.x = fmaxf((accv.x + s0.x) * dv + brc.x, 0.0f);                          \
    r.y = fmaxf((accv.y + s0.y) * dv + brc.y, 0.0f);                          \
    r.z = fmaxf((accv.z + s1.x) * dv + brc.z, 0.0f);                          \
    r.w = fmaxf((accv.w + s1.y) * dv + brc.w, 0.0f);                          \
    if (ADD_S) {                                                              \
      const uint2 sv2 = *(const uint2*)&hs16[(size_t)(n) * 32 + cl * 2];      \
      const float2 q0 = unpackh2(sv2.x);                                      \
      const float2 q1 = unpackh2(sv2.y);                                      \
      r.x += q0.x; r.y += q0.y; r.z += q1.x; r.w += q1.y;                     \
    }                                                                         \
    *(float4*)&h[(size_t)(n) * 64 + cl * 4] = r;                              \
  }
  FINAL(nA, accA)
  FINAL(nB, accB)
#undef FINAL
}

// -------- mean-pool: b is SORTED -> run-length accumulate, few atomics ------
__global__ __launch_bounds__(256) void k_pool(const float* __restrict__ h,
                                              const int* __restrict__ b,
                                              float* __restrict__ pool,
                                              float* __restrict__ cnt) {
  const int col = threadIdx.x & 63;
  const int wv  = threadIdx.x >> 6;
  const int node0 = (blockIdx.x * 4 + wv) * 64;
  if (node0 >= NN) return;
  const int node1 = min(node0 + 64, NN);
  int gcur = b[node0];
  float acc = 0.f;
  float run = 0.f;
  for (int n = node0; n < node1; ++n) {
    const int g = b[n];  // wave-uniform broadcast load
    if (g != gcur) {
      atomicAdd(&pool[(size_t)gcur * 64 + col], acc);
      if (col == 0) atomicAdd(&cnt[gcur], run);
      gcur = g; acc = 0.f; run = 0.f;
    }
    acc += h[(size_t)n * 64 + col];
    run += 1.f;
  }
  atomicAdd(&pool[(size_t)gcur * 64 + col], acc);
  if (col == 0) atomicAdd(&cnt[gcur], run);
}

// ---------------- MLP head ----------------
__global__ __launch_bounds__(64) void k_head(const float* __restrict__ pool,
                                             const float* __restrict__ cnt,
                                             const float* __restrict__ lin1W,
                                             const float* __restrict__ lin1b,
                                             const float* __restrict__ lin2W,
                                             const float* __restrict__ lin2b,
                                             float* __restrict__ out) {
  const int g = blockIdx.x;
  const int lane = threadIdx.x;
  const float c = fmaxf(cnt[g], 1.0f);
  float r = 0.f;
  if (lane < 32) {
    float s = lin1b[lane];
    const float* p = pool + (size_t)g * 64;
#pragma unroll 8
    for (int ci = 0; ci < 64; ++ci) s = fmaf(p[ci] / c, lin1W[ci * 32 + lane], s);
    r = fmaxf(s, 0.0f) * lin2W[lane];
  }
  for (int off = 32; off > 0; off >>= 1) r += __shfl_down(r, off, 64);
  if (lane == 0) out[g] = r + lin2b[0];
}

extern "C" void kernel_launch(void* const* d_in, const int* in_sizes, int n_in,
                              void* d_out, int out_size, void* d_ws, size_t ws_size,
                              hipStream_t stream) {
  const float* x     = (const float*)d_in[0];
  const int*   src   = (const int*)d_in[1];            // e_idx[0]
  const int*   dst   = ((const int*)d_in[1]) + NE;     // e_idx[1]
  const int*   b     = (const int*)d_in[2];
  const float* w0    = (const float*)d_in[3];
  const float* b0    = (const float*)d_in[4];
  const float* convW = (const float*)d_in[5];
  const float* convB = (const float*)d_in[6];
  const float* skipW = (const float*)d_in[7];
  const float* skipB = (const float*)d_in[8];
  const float* lin1W = (const float*)d_in[9];
  const float* lin1b = (const float*)d_in[10];
  const float* lin2W = (const float*)d_in[11];
  const float* lin2b = (const float*)d_in[12];
  float* out = (float*)d_out;

  // ---- workspace layout ----
  char* w = (char*)d_ws;
  const size_t NPAD = 102400;
  int*   cnt     = (int*)w;                  w += NPAD * 4;
  float* dinv    = (float*)w;                w += NPAD * 4;
  int*   row_ptr = (int*)w;                  w += NPAD * 4;
  int*   order   = (int*)w;                  w += NPAD * 4;
  int*   bcur    = (int*)w;                  w += 1024 * 4;
  int*   gcur    = (int*)w;                  w += 1024 * 4;
  int*   csr_src = (int*)w;                  w += (size_t)NBK * CAP * 4 + 4096;
  char*  big     = w;                        w += (size_t)NN * 32 * 4;     // 12.8MB
  u32*   hs16    = (u32*)w;                  w += (size_t)NN * 32 * 4;     // 12.8MB
  float* hA      = (float*)w;                w += (size_t)NN * 64 * 4;
  float* pool    = (float*)w;                w += (size_t)NG * 64 * 4;
  float* pcnt    = (float*)w;                w += (size_t)NG * 4;
  // ebuf (6.4MB, dead after k_csr) and hw16 (12.8MB) share `big`.
  u32* ebuf = (u32*)big;
  u32* hw16 = (u32*)big;

  // ---- zero workspace counters + pool (one kernel; pool+pcnt contiguous) ---
  k_zero<<<260, 256, 0, stream>>>(bcur, gcur, (float4*)pool);

  // ---- CSR build: bucket sort, octant-ordered, pre-scaled (once/launch) ----
  k_bin<<<NBLK_BIN, 256, 0, stream>>>(src, dst, bcur, ebuf);
  k_csr<<<NBK, 256, 0, stream>>>(bcur, ebuf, row_ptr, cnt, dinv, csr_src);
  // degree counting sort -> order[]
  const int OB = (NN + 255) / 256;  // 391
  k_obin<<<OB, 256, 0, stream>>>(cnt, gcur);
  k_oscan<<<1, 64, 0, stream>>>(gcur);
  k_oscat<<<OB, 256, 0, stream>>>(cnt, gcur, order);

  const int GT = (NN + 127) / 128;  // 782 tiles

  // ---- layer 0 ----
  k_gemm<NF, false><<<GT, 256, 0, stream>>>(x, w0, nullptr, nullptr, dinv,
                                            hw16, nullptr);
  k_agg<false><<<3125, 256, 0, stream>>>(hw16, nullptr, csr_src, row_ptr, cnt,
                                         dinv, b0, order, hA);
  // ---- layers 1..2 ----
  for (int i = 0; i < 2; ++i) {
    k_gemm<H, true><<<GT, 256, 0, stream>>>(hA, convW + (size_t)i * H * H,
                                            skipW + (size_t)i * H * H,
                                            skipB + (size_t)i * H, dinv, hw16,
                                            hs16);
    k_agg<true><<<3125, 256, 0, stream>>>(hw16, hs16, csr_src, row_ptr, cnt,
                                          dinv, convB + (size_t)i * H, order, hA);
  }

  // ---- mean pool + head ----
  k_pool<<<(NN / 256) + 1, 256, 0, stream>>>(hA, b, pool, pcnt);
  k_head<<<NG, 64, 0, stream>>>(pool, pcnt, lin1W, lin1b, lin2W, lin2b, out);
}

// Round 21
// 284.894 us; speedup vs baseline: 2.2706x; 2.2706x over previous
//
#include <hip/hip_runtime.h>
#include <hip/hip_fp16.h>

#define NN 100000      // nodes
#define NE 1600000     // edges
#define NF 128         // input features
#define H  64          // hidden channels
#define NG 4096        // graphs

#define NBK 512        // dst buckets
#define BKN 196        // nodes per bucket (512*196 >= NN)
#define CAP 4096       // edge capacity per bucket (avg 3125, sigma 56)
#define NBLK_BIN 256
#define CHUNK ((NE + NBLK_BIN - 1) / NBLK_BIN)   // 6250

typedef unsigned long long u64;
typedef unsigned int u32;
typedef __attribute__((ext_vector_type(2))) _Float16 h2;

__device__ inline u32 packh2(float x, float y) {
  __half2 h = __floats2half2_rn(x, y);
  return *reinterpret_cast<u32*>(&h);
}
__device__ inline float2 unpackh2(u32 u) {
  __half2 h = *reinterpret_cast<__half2*>(&u);
  return __half22float2(h);
}

#if __has_builtin(__builtin_amdgcn_fdot2)
__device__ inline float dot2(h2 a, h2 b, float c) {
  return __builtin_amdgcn_fdot2(a, b, c, false);
}
#else
__device__ inline float dot2(h2 a, h2 b, float c) {
  return fmaf((float)a.x, (float)b.x, fmaf((float)a.y, (float)b.y, c));
}
#endif

// ---- workspace zeroing (single cheap kernel; pool+pcnt contiguous) --------
__global__ __launch_bounds__(256) void k_zero(int* __restrict__ bcur,
                                              int* __restrict__ gcur,
                                              float4* __restrict__ poolv) {
  const int t = blockIdx.x * 256 + threadIdx.x;
  poolv[t] = make_float4(0.f, 0.f, 0.f, 0.f);
  if (t < NBK) bcur[t] = 0;
  if (t < 64) gcur[t] = 0;
}

// ---- phase 1: bucket-bin edges (u32 = dloc<<17 | src), block-local runs ----
// 256 blocks: per-(block,bucket) runs ~12 edges = 48 B -> low write amp.
__global__ __launch_bounds__(256) void k_bin(const int* __restrict__ src,
                                             const int* __restrict__ dst,
                                             int* __restrict__ bcur,
                                             u32* __restrict__ ebuf) {
  __shared__ int d_s[CHUNK];          // 25 KB: dst chunk staged once
  __shared__ int bcnt[NBK], bpos[NBK];
  const int e0 = blockIdx.x * CHUNK;
  const int e1 = min(e0 + CHUNK, NE);
  for (int i = threadIdx.x; i < NBK; i += 256) bcnt[i] = 0;
  __syncthreads();
  for (int e = e0 + threadIdx.x; e < e1; e += 256) {
    const int d = dst[e];
    d_s[e - e0] = d;
    atomicAdd(&bcnt[d / BKN], 1);
  }
  __syncthreads();
  for (int i = threadIdx.x; i < NBK; i += 256) {
    const int c = bcnt[i];
    if (c) bpos[i] = i * CAP + atomicAdd(&bcur[i], c);
  }
  __syncthreads();
  for (int e = e0 + threadIdx.x; e < e1; e += 256) {
    const int d = d_s[e - e0];
    const int bk = d / BKN;
    const int pos = atomicAdd(&bpos[bk], 1);
    ebuf[pos] = ((u32)(d - bk * BKN) << 17) | (u32)src[e];
  }
}

// ---- phase 2: per-bucket CSR build, src-octant-ordered adjacency ----------
// csr entries PRE-SCALED (src*16 = u64-row index of hw16).
// Bucket tail zero-padded so k_agg can over-read without clamping.
__global__ __launch_bounds__(256) void k_csr(const int* __restrict__ bcur,
                                             const u32* __restrict__ ebuf,
                                             int* __restrict__ row_ptr,
                                             int* __restrict__ cnt,
                                             float* __restrict__ dinv,
                                             int* __restrict__ csr_src) {
  __shared__ u32 eb_s[CAP];           // 16 KB
  __shared__ int deg[256], sc[256], cur[256];
  const int bk = blockIdx.x;
  const int nlo = bk * BKN;
  if (nlo >= NN) return;
  const int nloc = min(BKN, NN - nlo);
  const int cntE = bcur[bk];
  const int t = threadIdx.x;
  for (int e = t; e < cntE; e += 256) eb_s[e] = ebuf[(size_t)bk * CAP + e];
  deg[t] = 0;
  __syncthreads();
  for (int e = t; e < cntE; e += 256) atomicAdd(&deg[eb_s[e] >> 17], 1);
  __syncthreads();
  sc[t] = deg[t];
  __syncthreads();
  for (int off = 1; off < 256; off <<= 1) {
    const int add = (t >= off) ? sc[t - off] : 0;
    __syncthreads();
    sc[t] += add;
    __syncthreads();
  }
  const int excl = bk * CAP + sc[t] - deg[t];
  if (t < nloc) {
    row_ptr[nlo + t] = excl;
    cnt[nlo + t] = deg[t];
    dinv[nlo + t] = 1.0f / sqrtf((float)deg[t] + 1.0f);
  }
  cur[t] = excl;
  __syncthreads();
  for (int oct = 0; oct < 8; ++oct) {
    for (int e = t; e < cntE; e += 256) {
      const u32 ent = eb_s[e];
      const int s = (int)(ent & 0x1ffffu);
      if (((s >> 14) & 7) == oct) {
        const int pos = atomicAdd(&cur[ent >> 17], 1);
        csr_src[pos] = s << 4;  // pre-scaled (u64 units)
      }
    }
    __syncthreads();
  }
  // zero-pad tail so degree-mismatched groups can over-read safely
  for (int e = cntE + t; e < min(cntE + 64, CAP); e += 256)
    csr_src[bk * CAP + e] = 0;
}

// ---- degree counting sort: order[] groups nodes of equal/adjacent degree ---
__global__ __launch_bounds__(256) void k_obin(const int* __restrict__ cnt,
                                              int* __restrict__ gcur) {
  __shared__ int lh[64];
  const int t = threadIdx.x;
  if (t < 64) lh[t] = 0;
  __syncthreads();
  const int n = blockIdx.x * 256 + t;
  if (n < NN) atomicAdd(&lh[min(cnt[n], 63)], 1);
  __syncthreads();
  if (t < 64 && lh[t]) atomicAdd(&gcur[t], lh[t]);
}

__global__ __launch_bounds__(64) void k_oscan(int* __restrict__ gcur) {
  __shared__ int sh[64];
  const int t = threadIdx.x;
  const int v = gcur[t];
  sh[t] = v;
  __syncthreads();
  for (int off = 1; off < 64; off <<= 1) {
    const int a = (t >= off) ? sh[t - off] : 0;
    __syncthreads();
    sh[t] += a;
    __syncthreads();
  }
  gcur[t] = sh[t] - v;  // exclusive offset -> running cursor
}

__global__ __launch_bounds__(256) void k_oscat(const int* __restrict__ cnt,
                                               int* __restrict__ gcur,
                                               int* __restrict__ order) {
  __shared__ int lh[64], lo[64];
  const int t = threadIdx.x;
  if (t < 64) lh[t] = 0;
  __syncthreads();
  const int n = blockIdx.x * 256 + t;
  int bin = 0, loc = 0;
  if (n < NN) {
    bin = min(cnt[n], 63);
    loc = atomicAdd(&lh[bin], 1);
  }
  __syncthreads();
  if (t < 64 && lh[t]) lo[t] = atomicAdd(&gcur[t], lh[t]);
  __syncthreads();
  if (n < NN) order[lo[bin] + loc] = n;
}

// ---- node GEMM: fp16 inputs + v_dot2_f32_f16, fp32 accumulate -------------
// Block 256 threads = tile 128 rows x 64 cols; thread = 4 rows x 8 cols.
// A: XOR-swizzled quads (TXOR). B: per-col bank-quad offset WIDX.
// SK: skip result packed fp16 -> outS16.
// NOTE: inner-K loop must stay "#pragma unroll 2" -- full unroll blew VGPR
// to 256 and spilled (R20 regression: 39us -> 270us, 163MB scratch writes).
#define TXOR(row) ((((row) >> 3) & 3) << 2)
#define WIDX(c, kp) ((c) * WS + (((c) >> 3) << 2) + (kp))
template <int CI, bool SK>
__global__ __launch_bounds__(256) void k_gemm(const float* __restrict__ in,
                                              const float* __restrict__ W,
                                              const float* __restrict__ Ws,
                                              const float* __restrict__ bs,
                                              const float* __restrict__ dinv,
                                              u32* __restrict__ out16,
                                              u32* __restrict__ outS16) {
  constexpr int KP = CI / 2;          // half2 per row
  constexpr int RS = KP + 4;          // tin2 row stride
  constexpr int WS = KP + 4;          // wt2 col stride (+ per-col quad offset)
  __shared__ h2 tin2[128 * RS];
  __shared__ h2 wt2[64 * WS + 32];
  __shared__ h2 wsl2[SK ? 64 * WS + 32 : 1];
  union U2 { uint2 u; h2 h[2]; };
  union U4 { uint4 u; h2 h[4]; };

  const int row0 = blockIdx.x * 128;
  // stage weights (transposed, fp16)
  for (int i = threadIdx.x; i < 64 * KP; i += 256) {
    const int c = i & 63;
    const int kp = i >> 6;
    wt2[WIDX(c, kp)] = h2{(_Float16)W[(2 * kp) * 64 + c],
                          (_Float16)W[(2 * kp + 1) * 64 + c]};
    if (SK)
      wsl2[WIDX(c, kp)] = h2{(_Float16)Ws[(2 * kp) * 64 + c],
                             (_Float16)Ws[(2 * kp + 1) * 64 + c]};
  }
  // stage input tile fp32->fp16 (linear -> fully coalesced global reads)
  for (int s = 0; s < (128 * CI) / 1024; ++s) {
    const int idx = (s * 256 + threadIdx.x) * 4;
    const int r = idx / CI;
    const int k = idx % CI;
    const int rowc = min(row0 + r, NN - 1);
    const float4 v = *(const float4*)(in + (size_t)rowc * CI + k);
    U2 a;
    a.h[0] = h2{(_Float16)v.x, (_Float16)v.y};
    a.h[1] = h2{(_Float16)v.z, (_Float16)v.w};
    const int kp = (k >> 1) ^ TXOR(r);  // xor quad bits (pair stays in-quad)
    *(uint2*)&tin2[r * RS + kp] = a.u;
  }
  __syncthreads();

  const int rg = threadIdx.x >> 3;  // 0..31: 4-row group
  const int cg = threadIdx.x & 7;   // 0..7 : 8-col group
  float acc[4][8];
  float sacc[SK ? 4 : 1][8];
#pragma unroll
  for (int i = 0; i < 4; ++i)
#pragma unroll
    for (int j = 0; j < 8; ++j) acc[i][j] = 0.0f;
  if (SK) {
#pragma unroll
    for (int i = 0; i < 4; ++i)
#pragma unroll
      for (int j = 0; j < 8; ++j) sacc[i][j] = bs[cg * 8 + j];
  }

  const int tx = TXOR(rg * 4);  // same for the thread's 4 rows
#pragma unroll 2
  for (int kq = 0; kq < KP / 4; ++kq) {
    U4 A[4], B[8];
#pragma unroll
    for (int r = 0; r < 4; ++r)
      A[r].u = *(const uint4*)&tin2[(rg * 4 + r) * RS + ((kq * 4) ^ tx)];
#pragma unroll
    for (int c = 0; c < 8; ++c)
      B[c].u = *(const uint4*)&wt2[WIDX(cg * 8 + c, kq * 4)];
#pragma unroll
    for (int r = 0; r < 4; ++r)
#pragma unroll
      for (int c = 0; c < 8; ++c)
#pragma unroll
        for (int q = 0; q < 4; ++q)
          acc[r][c] = dot2(A[r].h[q], B[c].h[q], acc[r][c]);
    if (SK) {
      U4 C[8];
#pragma unroll
      for (int c = 0; c < 8; ++c)
        C[c].u = *(const uint4*)&wsl2[WIDX(cg * 8 + c, kq * 4)];
#pragma unroll
      for (int r = 0; r < 4; ++r)
#pragma unroll
        for (int c = 0; c < 8; ++c)
#pragma unroll
          for (int q = 0; q < 4; ++q)
            sacc[r][c] = dot2(A[r].h[q], C[c].h[q], sacc[r][c]);
    }
  }

#pragma unroll
  for (int i = 0; i < 4; ++i) {
    const int row = row0 + rg * 4 + i;
    if (row < NN) {
      const float dv = dinv[row];
      u32 o[4];
#pragma unroll
      for (int j = 0; j < 4; ++j)
        o[j] = packh2(acc[i][2 * j] * dv, acc[i][2 * j + 1] * dv);
      *(uint4*)&out16[(size_t)row * 32 + cg * 4] =
          make_uint4(o[0], o[1], o[2], o[3]);
      if (SK) {
        u32 so[4];
#pragma unroll
        for (int j = 0; j < 4; ++j)
          so[j] = packh2(sacc[i][2 * j], sacc[i][2 * j + 1]);
        *(uint4*)&outS16[(size_t)row * 32 + cg * 4] =
            make_uint4(so[0], so[1], so[2], so[3]);
      }
    }
  }
}

// ------- CSR aggregation + finalize (fp16 gather, 2 quads = 8 nodes/wave) ---
// Wave = 4 nodes x 16 lanes x 2 independent streams (A,B); staggered gather
// sub-batches keep ~16 gathers in flight sustained. gid REVERSED so
// high-degree (long-pole) blocks launch first; short blocks backfill.
template <bool ADD_S>
__global__ __launch_bounds__(256) void k_agg(const u32* __restrict__ hw16,
                                             const u32* __restrict__ hs16,
                                             const int* __restrict__ csr_src,
                                             const int* __restrict__ row_ptr,
                                             const int* __restrict__ cnt,
                                             const float* __restrict__ dinv,
                                             const float* __restrict__ bias,
                                             const int* __restrict__ order,
                                             float* __restrict__ h) {
  const int lane = threadIdx.x & 63;
  const int grp  = lane >> 4;        // node within quad
  const int cl   = lane & 15;        // col-quad index (4 fp16 = 8 B)
  const int wv   = threadIdx.x >> 6;
  const int gid  = 12499 - (blockIdx.x * 4 + wv);  // high-degree first
  const int nA = order[(gid * 2) * 4 + grp];
  const int nB = order[(gid * 2 + 1) * 4 + grp];
  const int begA = row_ptr[nA], degA = cnt[nA];
  const int begB = row_ptr[nB], degB = cnt[nB];
  int d1 = max(degA, degB);
  d1 = max(d1, __shfl_xor(d1, 16));
  const int dmax = max(d1, __shfl_xor(d1, 32));
  const u64* hw64 = (const u64*)hw16;
  const int gbase = grp << 4;
  float4 accA = make_float4(0.f, 0.f, 0.f, 0.f);
  float4 accB = make_float4(0.f, 0.f, 0.f, 0.f);

#define GATH(dst, idxv, K0, NK)                                               \
  _Pragma("unroll") for (int k = 0; k < NK; ++k) {                            \
    const int p = __shfl(idxv, gbase + (K0) + k);                             \
    dst[k] = *(const uint2*)&hw64[(size_t)(p + cl)];                          \
  }
#define ACC(uv, accv, deg, K0, NK)                                            \
  _Pragma("unroll") for (int k = 0; k < NK; ++k) {                            \
    const float m = ((i + (K0) + k) < (deg)) ? 1.0f : 0.0f;                   \
    const float2 f0 = unpackh2(uv[k].x);                                      \
    const float2 f1 = unpackh2(uv[k].y);                                      \
    accv.x = fmaf(f0.x, m, accv.x);                                           \
    accv.y = fmaf(f0.y, m, accv.y);                                           \
    accv.z = fmaf(f1.x, m, accv.z);                                           \
    accv.w = fmaf(f1.y, m, accv.w);                                           \
  }

  int i = 0;
  while (i + 16 <= dmax) {
    const int ivA = __builtin_nontemporal_load(&csr_src[begA + i + cl]);
    const int ivB = __builtin_nontemporal_load(&csr_src[begB + i + cl]);
    uint2 a0[8], b0[8], a1[8], b1[8];
    GATH(a0, ivA, 0, 8)
    GATH(b0, ivB, 0, 8)
    ACC(a0, accA, degA, 0, 8)
    GATH(a1, ivA, 8, 8)
    ACC(b0, accB, degB, 0, 8)
    GATH(b1, ivB, 8, 8)
    ACC(a1, accA, degA, 8, 8)
    ACC(b1, accB, degB, 8, 8)
    i += 16;
  }
  if (i < dmax) {
    const int ivA = __builtin_nontemporal_load(&csr_src[begA + i + cl]);
    const int ivB = __builtin_nontemporal_load(&csr_src[begB + i + cl]);
    const int rem = dmax - i;  // wave-uniform, 1..15
    int k0 = 0;
    if (rem & 8) {
      uint2 a[8], b[8];
      GATH(a, ivA, k0, 8) GATH(b, ivB, k0, 8)
      ACC(a, accA, degA, k0, 8) ACC(b, accB, degB, k0, 8)
      k0 += 8;
    }
    if (rem & 4) {
      uint2 a[4], b[4];
      GATH(a, ivA, k0, 4) GATH(b, ivB, k0, 4)
      ACC(a, accA, degA, k0, 4) ACC(b, accB, degB, k0, 4)
      k0 += 4;
    }
    if (rem & 2) {
      uint2 a[2], b[2];
      GATH(a, ivA, k0, 2) GATH(b, ivB, k0, 2)
      ACC(a, accA, degA, k0, 2) ACC(b, accB, degB, k0, 2)
      k0 += 2;
    }
    if (rem & 1) {
      uint2 a[1], b[1];
      GATH(a, ivA, k0, 1) GATH(b, ivB, k0, 1)
      ACC(a, accA, degA, k0, 1) ACC(b, accB, degB, k0, 1)
    }
  }
#undef GATH
#undef ACC

#define FINAL(n, accv)                                                        \
  {                                                                           \
    const uint2 sv = *(const uint2*)&hw64[(size_t)(n) * 16 + cl];             \
    const float2 s0 = unpackh2(sv.x);                                         \
    const float2 s1 = unpackh2(sv.y);                                         \
    const float dv = dinv[n];                                                 \
    const float4 brc = *(const float4*)&bias[cl * 4];                         \
    float4 r;                                                                 \
    r.x = fmaxf((accv.x + s0.x) * dv + brc.x, 0.0f);                          \
    r.y = fmaxf((accv.y + s0.y) * dv + brc.y, 0.0f);                          \
    r.z = fmaxf((accv.z + s1.x) * dv + brc.z, 0.0f);                          \
    r.w = fmaxf((accv.w + s1.y) * dv + brc.w, 0.0f);                          \
    if (ADD_S) {                                                              \
      const uint2 sv2 = *(const uint2*)&hs16[(size_t)(n) * 32 + cl * 2];      \
      const float2 q0 = unpackh2(sv2.x);                                      \
      const float2 q1 = unpackh2(sv2.y);                                      \
      r.x += q0.x; r.y += q0.y; r.z += q1.x; r.w += q1.y;                     \
    }                                                                         \
    *(float4*)&h[(size_t)(n) * 64 + cl * 4] = r;                              \
  }
  FINAL(nA, accA)
  FINAL(nB, accB)
#undef FINAL
}

// -------- mean-pool: b is SORTED -> run-length accumulate, few atomics ------
__global__ __launch_bounds__(256) void k_pool(const float* __restrict__ h,
                                              const int* __restrict__ b,
                                              float* __restrict__ pool,
                                              float* __restrict__ cnt) {
  const int col = threadIdx.x & 63;
  const int wv  = threadIdx.x >> 6;
  const int node0 = (blockIdx.x * 4 + wv) * 64;
  if (node0 >= NN) return;
  const int node1 = min(node0 + 64, NN);
  int gcur = b[node0];
  float acc = 0.f;
  float run = 0.f;
  for (int n = node0; n < node1; ++n) {
    const int g = b[n];  // wave-uniform broadcast load
    if (g != gcur) {
      atomicAdd(&pool[(size_t)gcur * 64 + col], acc);
      if (col == 0) atomicAdd(&cnt[gcur], run);
      gcur = g; acc = 0.f; run = 0.f;
    }
    acc += h[(size_t)n * 64 + col];
    run += 1.f;
  }
  atomicAdd(&pool[(size_t)gcur * 64 + col], acc);
  if (col == 0) atomicAdd(&cnt[gcur], run);
}

// ---------------- MLP head ----------------
__global__ __launch_bounds__(64) void k_head(const float* __restrict__ pool,
                                             const float* __restrict__ cnt,
                                             const float* __restrict__ lin1W,
                                             const float* __restrict__ lin1b,
                                             const float* __restrict__ lin2W,
                                             const float* __restrict__ lin2b,
                                             float* __restrict__ out) {
  const int g = blockIdx.x;
  const int lane = threadIdx.x;
  const float c = fmaxf(cnt[g], 1.0f);
  float r = 0.f;
  if (lane < 32) {
    float s = lin1b[lane];
    const float* p = pool + (size_t)g * 64;
#pragma unroll 8
    for (int ci = 0; ci < 64; ++ci) s = fmaf(p[ci] / c, lin1W[ci * 32 + lane], s);
    r = fmaxf(s, 0.0f) * lin2W[lane];
  }
  for (int off = 32; off > 0; off >>= 1) r += __shfl_down(r, off, 64);
  if (lane == 0) out[g] = r + lin2b[0];
}

extern "C" void kernel_launch(void* const* d_in, const int* in_sizes, int n_in,
                              void* d_out, int out_size, void* d_ws, size_t ws_size,
                              hipStream_t stream) {
  const float* x     = (const float*)d_in[0];
  const int*   src   = (const int*)d_in[1];            // e_idx[0]
  const int*   dst   = ((const int*)d_in[1]) + NE;     // e_idx[1]
  const int*   b     = (const int*)d_in[2];
  const float* w0    = (const float*)d_in[3];
  const float* b0    = (const float*)d_in[4];
  const float* convW = (const float*)d_in[5];
  const float* convB = (const float*)d_in[6];
  const float* skipW = (const float*)d_in[7];
  const float* skipB = (const float*)d_in[8];
  const float* lin1W = (const float*)d_in[9];
  const float* lin1b = (const float*)d_in[10];
  const float* lin2W = (const float*)d_in[11];
  const float* lin2b = (const float*)d_in[12];
  float* out = (float*)d_out;

  // ---- workspace layout ----
  char* w = (char*)d_ws;
  const size_t NPAD = 102400;
  int*   cnt     = (int*)w;                  w += NPAD * 4;
  float* dinv    = (float*)w;                w += NPAD * 4;
  int*   row_ptr = (int*)w;                  w += NPAD * 4;
  int*   order   = (int*)w;                  w += NPAD * 4;
  int*   bcur    = (int*)w;                  w += 1024 * 4;
  int*   gcur    = (int*)w;                  w += 1024 * 4;
  int*   csr_src = (int*)w;                  w += (size_t)NBK * CAP * 4 + 4096;
  char*  big     = w;                        w += (size_t)NN * 32 * 4;     // 12.8MB
  u32*   hs16    = (u32*)w;                  w += (size_t)NN * 32 * 4;     // 12.8MB
  float* hA      = (float*)w;                w += (size_t)NN * 64 * 4;
  float* pool    = (float*)w;                w += (size_t)NG * 64 * 4;
  float* pcnt    = (float*)w;                w += (size_t)NG * 4;
  // ebuf (6.4MB, dead after k_csr) and hw16 (12.8MB) share `big`.
  u32* ebuf = (u32*)big;
  u32* hw16 = (u32*)big;

  // ---- zero workspace counters + pool (one kernel; pool+pcnt contiguous) ---
  k_zero<<<260, 256, 0, stream>>>(bcur, gcur, (float4*)pool);

  // ---- CSR build: bucket sort, octant-ordered, pre-scaled (once/launch) ----
  k_bin<<<NBLK_BIN, 256, 0, stream>>>(src, dst, bcur, ebuf);
  k_csr<<<NBK, 256, 0, stream>>>(bcur, ebuf, row_ptr, cnt, dinv, csr_src);
  // degree counting sort -> order[]
  const int OB = (NN + 255) / 256;  // 391
  k_obin<<<OB, 256, 0, stream>>>(cnt, gcur);
  k_oscan<<<1, 64, 0, stream>>>(gcur);
  k_oscat<<<OB, 256, 0, stream>>>(cnt, gcur, order);

  const int GT = (NN + 127) / 128;  // 782 tiles

  // ---- layer 0 ----
  k_gemm<NF, false><<<GT, 256, 0, stream>>>(x, w0, nullptr, nullptr, dinv,
                                            hw16, nullptr);
  k_agg<false><<<3125, 256, 0, stream>>>(hw16, nullptr, csr_src, row_ptr, cnt,
                                         dinv, b0, order, hA);
  // ---- layers 1..2 ----
  for (int i = 0; i < 2; ++i) {
    k_gemm<H, true><<<GT, 256, 0, stream>>>(hA, convW + (size_t)i * H * H,
                                            skipW + (size_t)i * H * H,
                                            skipB + (size_t)i * H, dinv, hw16,
                                            hs16);
    k_agg<true><<<3125, 256, 0, stream>>>(hw16, hs16, csr_src, row_ptr, cnt,
                                          dinv, convB + (size_t)i * H, order, hA);
  }

  // ---- mean pool + head ----
  k_pool<<<(NN / 256) + 1, 256, 0, stream>>>(hA, b, pool, pcnt);
  k_head<<<NG, 64, 0, stream>>>(pool, pcnt, lin1W, lin1b, lin2W, lin2b, out);
}

// Round 22
// 277.371 us; speedup vs baseline: 2.3322x; 1.0271x over previous
//
#include <hip/hip_runtime.h>
#include <hip/hip_fp16.h>

#define NN 100000      // nodes
#define NE 1600000     // edges
#define NF 128         // input features
#define H  64          // hidden channels
#define NG 4096        // graphs

#define NBK 512        // dst buckets
#define BKN 196        // nodes per bucket (512*196 >= NN)
#define CAP 4096       // edge capacity per bucket (avg 3125, sigma 56)
#define NBLK_BIN 256
#define CHUNK ((NE + NBLK_BIN - 1) / NBLK_BIN)   // 6250

typedef unsigned long long u64;
typedef unsigned int u32;
typedef __attribute__((ext_vector_type(2))) _Float16 h2;

__device__ inline u32 packh2(float x, float y) {
  __half2 h = __floats2half2_rn(x, y);
  return *reinterpret_cast<u32*>(&h);
}
__device__ inline float2 unpackh2(u32 u) {
  __half2 h = *reinterpret_cast<__half2*>(&u);
  return __half22float2(h);
}

#if __has_builtin(__builtin_amdgcn_fdot2)
__device__ inline float dot2(h2 a, h2 b, float c) {
  return __builtin_amdgcn_fdot2(a, b, c, false);
}
#else
__device__ inline float dot2(h2 a, h2 b, float c) {
  return fmaf((float)a.x, (float)b.x, fmaf((float)a.y, (float)b.y, c));
}
#endif

// ---- workspace zeroing (single cheap kernel; pool+pcnt contiguous) --------
__global__ __launch_bounds__(256) void k_zero(int* __restrict__ bcur,
                                              int* __restrict__ gcur,
                                              float4* __restrict__ poolv) {
  const int t = blockIdx.x * 256 + threadIdx.x;
  poolv[t] = make_float4(0.f, 0.f, 0.f, 0.f);
  if (t < NBK) bcur[t] = 0;
  if (t < 64) gcur[t] = 0;
}

// ---- phase 1: bucket-bin edges (u32 = dloc<<17 | src), block-local runs ----
// 256 blocks: per-(block,bucket) runs ~12 edges = 48 B -> low write amp.
__global__ __launch_bounds__(256) void k_bin(const int* __restrict__ src,
                                             const int* __restrict__ dst,
                                             int* __restrict__ bcur,
                                             u32* __restrict__ ebuf) {
  __shared__ int d_s[CHUNK];          // 25 KB: dst chunk staged once
  __shared__ int bcnt[NBK], bpos[NBK];
  const int e0 = blockIdx.x * CHUNK;
  const int e1 = min(e0 + CHUNK, NE);
  for (int i = threadIdx.x; i < NBK; i += 256) bcnt[i] = 0;
  __syncthreads();
  for (int e = e0 + threadIdx.x; e < e1; e += 256) {
    const int d = dst[e];
    d_s[e - e0] = d;
    atomicAdd(&bcnt[d / BKN], 1);
  }
  __syncthreads();
  for (int i = threadIdx.x; i < NBK; i += 256) {
    const int c = bcnt[i];
    if (c) bpos[i] = i * CAP + atomicAdd(&bcur[i], c);
  }
  __syncthreads();
  for (int e = e0 + threadIdx.x; e < e1; e += 256) {
    const int d = d_s[e - e0];
    const int bk = d / BKN;
    const int pos = atomicAdd(&bpos[bk], 1);
    ebuf[pos] = ((u32)(d - bk * BKN) << 17) | (u32)src[e];
  }
}

// ---- phase 2: per-bucket CSR build, src-octant-ordered adjacency ----------
// csr entries PRE-SCALED (src*16 = u64-row index of hw16).
// Bucket tail zero-padded so k_agg can over-read without clamping.
__global__ __launch_bounds__(256) void k_csr(const int* __restrict__ bcur,
                                             const u32* __restrict__ ebuf,
                                             int* __restrict__ row_ptr,
                                             int* __restrict__ cnt,
                                             float* __restrict__ dinv,
                                             int* __restrict__ csr_src) {
  __shared__ u32 eb_s[CAP];           // 16 KB
  __shared__ int deg[256], sc[256], cur[256];
  const int bk = blockIdx.x;
  const int nlo = bk * BKN;
  if (nlo >= NN) return;
  const int nloc = min(BKN, NN - nlo);
  const int cntE = bcur[bk];
  const int t = threadIdx.x;
  for (int e = t; e < cntE; e += 256) eb_s[e] = ebuf[(size_t)bk * CAP + e];
  deg[t] = 0;
  __syncthreads();
  for (int e = t; e < cntE; e += 256) atomicAdd(&deg[eb_s[e] >> 17], 1);
  __syncthreads();
  sc[t] = deg[t];
  __syncthreads();
  for (int off = 1; off < 256; off <<= 1) {
    const int add = (t >= off) ? sc[t - off] : 0;
    __syncthreads();
    sc[t] += add;
    __syncthreads();
  }
  const int excl = bk * CAP + sc[t] - deg[t];
  if (t < nloc) {
    row_ptr[nlo + t] = excl;
    cnt[nlo + t] = deg[t];
    dinv[nlo + t] = 1.0f / sqrtf((float)deg[t] + 1.0f);
  }
  cur[t] = excl;
  __syncthreads();
  for (int oct = 0; oct < 8; ++oct) {
    for (int e = t; e < cntE; e += 256) {
      const u32 ent = eb_s[e];
      const int s = (int)(ent & 0x1ffffu);
      if (((s >> 14) & 7) == oct) {
        const int pos = atomicAdd(&cur[ent >> 17], 1);
        csr_src[pos] = s << 4;  // pre-scaled (u64 units)
      }
    }
    __syncthreads();
  }
  // zero-pad tail so degree-mismatched groups can over-read safely
  for (int e = cntE + t; e < min(cntE + 64, CAP); e += 256)
    csr_src[bk * CAP + e] = 0;
}

// ---- degree counting sort: order[] groups nodes of equal/adjacent degree ---
__global__ __launch_bounds__(256) void k_obin(const int* __restrict__ cnt,
                                              int* __restrict__ gcur) {
  __shared__ int lh[64];
  const int t = threadIdx.x;
  if (t < 64) lh[t] = 0;
  __syncthreads();
  const int n = blockIdx.x * 256 + t;
  if (n < NN) atomicAdd(&lh[min(cnt[n], 63)], 1);
  __syncthreads();
  if (t < 64 && lh[t]) atomicAdd(&gcur[t], lh[t]);
}

__global__ __launch_bounds__(64) void k_oscan(int* __restrict__ gcur) {
  __shared__ int sh[64];
  const int t = threadIdx.x;
  const int v = gcur[t];
  sh[t] = v;
  __syncthreads();
  for (int off = 1; off < 64; off <<= 1) {
    const int a = (t >= off) ? sh[t - off] : 0;
    __syncthreads();
    sh[t] += a;
    __syncthreads();
  }
  gcur[t] = sh[t] - v;  // exclusive offset -> running cursor
}

__global__ __launch_bounds__(256) void k_oscat(const int* __restrict__ cnt,
                                               int* __restrict__ gcur,
                                               int* __restrict__ order) {
  __shared__ int lh[64], lo[64];
  const int t = threadIdx.x;
  if (t < 64) lh[t] = 0;
  __syncthreads();
  const int n = blockIdx.x * 256 + t;
  int bin = 0, loc = 0;
  if (n < NN) {
    bin = min(cnt[n], 63);
    loc = atomicAdd(&lh[bin], 1);
  }
  __syncthreads();
  if (t < 64 && lh[t]) lo[t] = atomicAdd(&gcur[t], lh[t]);
  __syncthreads();
  if (n < NN) order[lo[bin] + loc] = n;
}

// ---- node GEMM: fp16 inputs + v_dot2_f32_f16, fp32 accumulate -------------
// Block 256 threads = tile 64 rows x 64 cols; thread = 2 rows x 8 cols.
// 64-row tile halves tin2 LDS (L0: ~35 KB -> 4 blocks/CU; SK: ~28 KB -> 5).
// A: XOR-swizzled quads (TXOR); 2-row groups land on 8 distinct bank-quads
//    ({0,8,16,24} base + {0,4} TXOR spread). B: WIDX bank-quad offset.
// SK: skip result packed fp16 -> outS16.
// NOTE: inner-K loop must stay "#pragma unroll 2" -- full unroll blew VGPR
// to 256 and spilled (R20 regression: 39us -> 270us, 163MB scratch writes).
#define TXOR(row) ((((row) >> 3) & 3) << 2)
#define WIDX(c, kp) ((c) * WS + (((c) >> 3) << 2) + (kp))
template <int CI, bool SK>
__global__ __launch_bounds__(256) void k_gemm(const float* __restrict__ in,
                                              const float* __restrict__ W,
                                              const float* __restrict__ Ws,
                                              const float* __restrict__ bs,
                                              const float* __restrict__ dinv,
                                              u32* __restrict__ out16,
                                              u32* __restrict__ outS16) {
  constexpr int KP = CI / 2;          // half2 per row
  constexpr int RS = KP + 4;          // tin2 row stride
  constexpr int WS = KP + 4;          // wt2 col stride (+ per-col quad offset)
  __shared__ h2 tin2[64 * RS];
  __shared__ h2 wt2[64 * WS + 32];
  __shared__ h2 wsl2[SK ? 64 * WS + 32 : 1];
  union U2 { uint2 u; h2 h[2]; };
  union U4 { uint4 u; h2 h[4]; };

  const int row0 = blockIdx.x * 64;
  // stage weights (transposed, fp16)
  for (int i = threadIdx.x; i < 64 * KP; i += 256) {
    const int c = i & 63;
    const int kp = i >> 6;
    wt2[WIDX(c, kp)] = h2{(_Float16)W[(2 * kp) * 64 + c],
                          (_Float16)W[(2 * kp + 1) * 64 + c]};
    if (SK)
      wsl2[WIDX(c, kp)] = h2{(_Float16)Ws[(2 * kp) * 64 + c],
                             (_Float16)Ws[(2 * kp + 1) * 64 + c]};
  }
  // stage input tile fp32->fp16 (linear -> fully coalesced global reads)
  for (int s = 0; s < (64 * CI) / 1024; ++s) {
    const int idx = (s * 256 + threadIdx.x) * 4;
    const int r = idx / CI;
    const int k = idx % CI;
    const int rowc = min(row0 + r, NN - 1);
    const float4 v = *(const float4*)(in + (size_t)rowc * CI + k);
    U2 a;
    a.h[0] = h2{(_Float16)v.x, (_Float16)v.y};
    a.h[1] = h2{(_Float16)v.z, (_Float16)v.w};
    const int kp = (k >> 1) ^ TXOR(r);  // xor quad bits (pair stays in-quad)
    *(uint2*)&tin2[r * RS + kp] = a.u;
  }
  __syncthreads();

  const int rg = threadIdx.x >> 3;  // 0..31: 2-row group
  const int cg = threadIdx.x & 7;   // 0..7 : 8-col group
  float acc[2][8];
  float sacc[SK ? 2 : 1][8];
#pragma unroll
  for (int i = 0; i < 2; ++i)
#pragma unroll
    for (int j = 0; j < 8; ++j) acc[i][j] = 0.0f;
  if (SK) {
#pragma unroll
    for (int i = 0; i < 2; ++i)
#pragma unroll
      for (int j = 0; j < 8; ++j) sacc[i][j] = bs[cg * 8 + j];
  }

  const int tx = TXOR(rg * 2);  // same for the thread's 2 rows (2rg even)
#pragma unroll 2
  for (int kq = 0; kq < KP / 4; ++kq) {
    U4 A[2], B[8];
#pragma unroll
    for (int r = 0; r < 2; ++r)
      A[r].u = *(const uint4*)&tin2[(rg * 2 + r) * RS + ((kq * 4) ^ tx)];
#pragma unroll
    for (int c = 0; c < 8; ++c)
      B[c].u = *(const uint4*)&wt2[WIDX(cg * 8 + c, kq * 4)];
#pragma unroll
    for (int r = 0; r < 2; ++r)
#pragma unroll
      for (int c = 0; c < 8; ++c)
#pragma unroll
        for (int q = 0; q < 4; ++q)
          acc[r][c] = dot2(A[r].h[q], B[c].h[q], acc[r][c]);
    if (SK) {
      U4 C[8];
#pragma unroll
      for (int c = 0; c < 8; ++c)
        C[c].u = *(const uint4*)&wsl2[WIDX(cg * 8 + c, kq * 4)];
#pragma unroll
      for (int r = 0; r < 2; ++r)
#pragma unroll
        for (int c = 0; c < 8; ++c)
#pragma unroll
          for (int q = 0; q < 4; ++q)
            sacc[r][c] = dot2(A[r].h[q], C[c].h[q], sacc[r][c]);
    }
  }

#pragma unroll
  for (int i = 0; i < 2; ++i) {
    const int row = row0 + rg * 2 + i;
    if (row < NN) {
      const float dv = dinv[row];
      u32 o[4];
#pragma unroll
      for (int j = 0; j < 4; ++j)
        o[j] = packh2(acc[i][2 * j] * dv, acc[i][2 * j + 1] * dv);
      *(uint4*)&out16[(size_t)row * 32 + cg * 4] =
          make_uint4(o[0], o[1], o[2], o[3]);
      if (SK) {
        u32 so[4];
#pragma unroll
        for (int j = 0; j < 4; ++j)
          so[j] = packh2(sacc[i][2 * j], sacc[i][2 * j + 1]);
        *(uint4*)&outS16[(size_t)row * 32 + cg * 4] =
            make_uint4(so[0], so[1], so[2], so[3]);
      }
    }
  }
}

// ------- CSR aggregation + finalize (fp16 gather, 2 quads = 8 nodes/wave) ---
// Wave = 4 nodes x 16 lanes x 2 independent streams (A,B); staggered gather
// sub-batches keep ~16 gathers in flight sustained. gid REVERSED so
// high-degree (long-pole) blocks launch first; short blocks backfill.
template <bool ADD_S>
__global__ __launch_bounds__(256) void k_agg(const u32* __restrict__ hw16,
                                             const u32* __restrict__ hs16,
                                             const int* __restrict__ csr_src,
                                             const int* __restrict__ row_ptr,
                                             const int* __restrict__ cnt,
                                             const float* __restrict__ dinv,
                                             const float* __restrict__ bias,
                                             const int* __restrict__ order,
                                             float* __restrict__ h) {
  const int lane = threadIdx.x & 63;
  const int grp  = lane >> 4;        // node within quad
  const int cl   = lane & 15;        // col-quad index (4 fp16 = 8 B)
  const int wv   = threadIdx.x >> 6;
  const int gid  = 12499 - (blockIdx.x * 4 + wv);  // high-degree first
  const int nA = order[(gid * 2) * 4 + grp];
  const int nB = order[(gid * 2 + 1) * 4 + grp];
  const int begA = row_ptr[nA], degA = cnt[nA];
  const int begB = row_ptr[nB], degB = cnt[nB];
  int d1 = max(degA, degB);
  d1 = max(d1, __shfl_xor(d1, 16));
  const int dmax = max(d1, __shfl_xor(d1, 32));
  const u64* hw64 = (const u64*)hw16;
  const int gbase = grp << 4;
  float4 accA = make_float4(0.f, 0.f, 0.f, 0.f);
  float4 accB = make_float4(0.f, 0.f, 0.f, 0.f);

#define GATH(dst, idxv, K0, NK)                                               \
  _Pragma("unroll") for (int k = 0; k < NK; ++k) {                            \
    const int p = __shfl(idxv, gbase + (K0) + k);                             \
    dst[k] = *(const uint2*)&hw64[(size_t)(p + cl)];                          \
  }
#define ACC(uv, accv, deg, K0, NK)                                            \
  _Pragma("unroll") for (int k = 0; k < NK; ++k) {                            \
    const float m = ((i + (K0) + k) < (deg)) ? 1.0f : 0.0f;                   \
    const float2 f0 = unpackh2(uv[k].x);                                      \
    const float2 f1 = unpackh2(uv[k].y);                                      \
    accv.x = fmaf(f0.x, m, accv.x);                                           \
    accv.y = fmaf(f0.y, m, accv.y);                                           \
    accv.z = fmaf(f1.x, m, accv.z);                                           \
    accv.w = fmaf(f1.y, m, accv.w);                                           \
  }

  int i = 0;
  while (i + 16 <= dmax) {
    const int ivA = __builtin_nontemporal_load(&csr_src[begA + i + cl]);
    const int ivB = __builtin_nontemporal_load(&csr_src[begB + i + cl]);
    uint2 a0[8], b0[8], a1[8], b1[8];
    GATH(a0, ivA, 0, 8)
    GATH(b0, ivB, 0, 8)
    ACC(a0, accA, degA, 0, 8)
    GATH(a1, ivA, 8, 8)
    ACC(b0, accB, degB, 0, 8)
    GATH(b1, ivB, 8, 8)
    ACC(a1, accA, degA, 8, 8)
    ACC(b1, accB, degB, 8, 8)
    i += 16;
  }
  if (i < dmax) {
    const int ivA = __builtin_nontemporal_load(&csr_src[begA + i + cl]);
    const int ivB = __builtin_nontemporal_load(&csr_src[begB + i + cl]);
    const int rem = dmax - i;  // wave-uniform, 1..15
    int k0 = 0;
    if (rem & 8) {
      uint2 a[8], b[8];
      GATH(a, ivA, k0, 8) GATH(b, ivB, k0, 8)
      ACC(a, accA, degA, k0, 8) ACC(b, accB, degB, k0, 8)
      k0 += 8;
    }
    if (rem & 4) {
      uint2 a[4], b[4];
      GATH(a, ivA, k0, 4) GATH(b, ivB, k0, 4)
      ACC(a, accA, degA, k0, 4) ACC(b, accB, degB, k0, 4)
      k0 += 4;
    }
    if (rem & 2) {
      uint2 a[2], b[2];
      GATH(a, ivA, k0, 2) GATH(b, ivB, k0, 2)
      ACC(a, accA, degA, k0, 2) ACC(b, accB, degB, k0, 2)
      k0 += 2;
    }
    if (rem & 1) {
      uint2 a[1], b[1];
      GATH(a, ivA, k0, 1) GATH(b, ivB, k0, 1)
      ACC(a, accA, degA, k0, 1) ACC(b, accB, degB, k0, 1)
    }
  }
#undef GATH
#undef ACC

#define FINAL(n, accv)                                                        \
  {                                                                           \
    const uint2 sv = *(const uint2*)&hw64[(size_t)(n) * 16 + cl];             \
    const float2 s0 = unpackh2(sv.x);                                         \
    const float2 s1 = unpackh2(sv.y);                                         \
    const float dv = dinv[n];                                                 \
    const float4 brc = *(const float4*)&bias[cl * 4];                         \
    float4 r;                                                                 \
    r.x = fmaxf((accv.x + s0.x) * dv + brc.x, 0.0f);                          \
    r.y = fmaxf((accv.y + s0.y) * dv + brc.y, 0.0f);                          \
    r.z = fmaxf((accv.z + s1.x) * dv + brc.z, 0.0f);                          \
    r.w = fmaxf((accv.w + s1.y) * dv + brc.w, 0.0f);                          \
    if (ADD_S) {                                                              \
      const uint2 sv2 = *(const uint2*)&hs16[(size_t)(n) * 32 + cl * 2];      \
      const float2 q0 = unpackh2(sv2.x);                                      \
      const float2 q1 = unpackh2(sv2.y);                                      \
      r.x += q0.x; r.y += q0.y; r.z += q1.x; r.w += q1.y;                     \
    }                                                                         \
    *(float4*)&h[(size_t)(n) * 64 + cl * 4] = r;                              \
  }
  FINAL(nA, accA)
  FINAL(nB, accB)
#undef FINAL
}

// -------- mean-pool: b is SORTED -> run-length accumulate, few atomics ------
__global__ __launch_bounds__(256) void k_pool(const float* __restrict__ h,
                                              const int* __restrict__ b,
                                              float* __restrict__ pool,
                                              float* __restrict__ cnt) {
  const int col = threadIdx.x & 63;
  const int wv  = threadIdx.x >> 6;
  const int node0 = (blockIdx.x * 4 + wv) * 64;
  if (node0 >= NN) return;
  const int node1 = min(node0 + 64, NN);
  int gcur = b[node0];
  float acc = 0.f;
  float run = 0.f;
  for (int n = node0; n < node1; ++n) {
    const int g = b[n];  // wave-uniform broadcast load
    if (g != gcur) {
      atomicAdd(&pool[(size_t)gcur * 64 + col], acc);
      if (col == 0) atomicAdd(&cnt[gcur], run);
      gcur = g; acc = 0.f; run = 0.f;
    }
    acc += h[(size_t)n * 64 + col];
    run += 1.f;
  }
  atomicAdd(&pool[(size_t)gcur * 64 + col], acc);
  if (col == 0) atomicAdd(&cnt[gcur], run);
}

// ---------------- MLP head ----------------
__global__ __launch_bounds__(64) void k_head(const float* __restrict__ pool,
                                             const float* __restrict__ cnt,
                                             const float* __restrict__ lin1W,
                                             const float* __restrict__ lin1b,
                                             const float* __restrict__ lin2W,
                                             const float* __restrict__ lin2b,
                                             float* __restrict__ out) {
  const int g = blockIdx.x;
  const int lane = threadIdx.x;
  const float c = fmaxf(cnt[g], 1.0f);
  float r = 0.f;
  if (lane < 32) {
    float s = lin1b[lane];
    const float* p = pool + (size_t)g * 64;
#pragma unroll 8
    for (int ci = 0; ci < 64; ++ci) s = fmaf(p[ci] / c, lin1W[ci * 32 + lane], s);
    r = fmaxf(s, 0.0f) * lin2W[lane];
  }
  for (int off = 32; off > 0; off >>= 1) r += __shfl_down(r, off, 64);
  if (lane == 0) out[g] = r + lin2b[0];
}

extern "C" void kernel_launch(void* const* d_in, const int* in_sizes, int n_in,
                              void* d_out, int out_size, void* d_ws, size_t ws_size,
                              hipStream_t stream) {
  const float* x     = (const float*)d_in[0];
  const int*   src   = (const int*)d_in[1];            // e_idx[0]
  const int*   dst   = ((const int*)d_in[1]) + NE;     // e_idx[1]
  const int*   b     = (const int*)d_in[2];
  const float* w0    = (const float*)d_in[3];
  const float* b0    = (const float*)d_in[4];
  const float* convW = (const float*)d_in[5];
  const float* convB = (const float*)d_in[6];
  const float* skipW = (const float*)d_in[7];
  const float* skipB = (const float*)d_in[8];
  const float* lin1W = (const float*)d_in[9];
  const float* lin1b = (const float*)d_in[10];
  const float* lin2W = (const float*)d_in[11];
  const float* lin2b = (const float*)d_in[12];
  float* out = (float*)d_out;

  // ---- workspace layout ----
  char* w = (char*)d_ws;
  const size_t NPAD = 102400;
  int*   cnt     = (int*)w;                  w += NPAD * 4;
  float* dinv    = (float*)w;                w += NPAD * 4;
  int*   row_ptr = (int*)w;                  w += NPAD * 4;
  int*   order   = (int*)w;                  w += NPAD * 4;
  int*   bcur    = (int*)w;                  w += 1024 * 4;
  int*   gcur    = (int*)w;                  w += 1024 * 4;
  int*   csr_src = (int*)w;                  w += (size_t)NBK * CAP * 4 + 4096;
  char*  big     = w;                        w += (size_t)NN * 32 * 4;     // 12.8MB
  u32*   hs16    = (u32*)w;                  w += (size_t)NN * 32 * 4;     // 12.8MB
  float* hA      = (float*)w;                w += (size_t)NN * 64 * 4;
  float* pool    = (float*)w;                w += (size_t)NG * 64 * 4;
  float* pcnt    = (float*)w;                w += (size_t)NG * 4;
  // ebuf (6.4MB, dead after k_csr) and hw16 (12.8MB) share `big`.
  u32* ebuf = (u32*)big;
  u32* hw16 = (u32*)big;

  // ---- zero workspace counters + pool (one kernel; pool+pcnt contiguous) ---
  k_zero<<<260, 256, 0, stream>>>(bcur, gcur, (float4*)pool);

  // ---- CSR build: bucket sort, octant-ordered, pre-scaled (once/launch) ----
  k_bin<<<NBLK_BIN, 256, 0, stream>>>(src, dst, bcur, ebuf);
  k_csr<<<NBK, 256, 0, stream>>>(bcur, ebuf, row_ptr, cnt, dinv, csr_src);
  // degree counting sort -> order[]
  const int OB = (NN + 255) / 256;  // 391
  k_obin<<<OB, 256, 0, stream>>>(cnt, gcur);
  k_oscan<<<1, 64, 0, stream>>>(gcur);
  k_oscat<<<OB, 256, 0, stream>>>(cnt, gcur, order);

  const int GT = (NN + 63) / 64;  // 1563 tiles

  // ---- layer 0 ----
  k_gemm<NF, false><<<GT, 256, 0, stream>>>(x, w0, nullptr, nullptr, dinv,
                                            hw16, nullptr);
  k_agg<false><<<3125, 256, 0, stream>>>(hw16, nullptr, csr_src, row_ptr, cnt,
                                         dinv, b0, order, hA);
  // ---- layers 1..2 ----
  for (int i = 0; i < 2; ++i) {
    k_gemm<H, true><<<GT, 256, 0, stream>>>(hA, convW + (size_t)i * H * H,
                                            skipW + (size_t)i * H * H,
                                            skipB + (size_t)i * H, dinv, hw16,
                                            hs16);
    k_agg<true><<<3125, 256, 0, stream>>>(hw16, hs16, csr_src, row_ptr, cnt,
                                          dinv, convB + (size_t)i * H, order, hA);
  }

  // ---- mean pool + head ----
  k_pool<<<(NN / 256) + 1, 256, 0, stream>>>(hA, b, pool, pcnt);
  k_head<<<NG, 64, 0, stream>>>(pool, pcnt, lin1W, lin1b, lin2W, lin2b, out);
}

// Round 23
// 275.491 us; speedup vs baseline: 2.3481x; 1.0068x over previous
//
#include <hip/hip_runtime.h>
#include <hip/hip_fp16.h>

#define NN 100000      // nodes
#define NE 1600000     // edges
#define NF 128         // input features
#define H  64          // hidden channels
#define NG 4096        // graphs

#define NBK 512        // dst buckets
#define BKN 196        // nodes per bucket (512*196 >= NN)
#define CAP 4096       // edge capacity per bucket (avg 3125, sigma 56)
#define NBLK_BIN 256
#define CHUNK ((NE + NBLK_BIN - 1) / NBLK_BIN)   // 6250

typedef unsigned long long u64;
typedef unsigned int u32;
typedef __attribute__((ext_vector_type(2))) _Float16 h2;

__device__ inline u32 packh2(float x, float y) {
  __half2 h = __floats2half2_rn(x, y);
  return *reinterpret_cast<u32*>(&h);
}
__device__ inline float2 unpackh2(u32 u) {
  __half2 h = *reinterpret_cast<__half2*>(&u);
  return __half22float2(h);
}

#if __has_builtin(__builtin_amdgcn_fdot2)
__device__ inline float dot2(h2 a, h2 b, float c) {
  return __builtin_amdgcn_fdot2(a, b, c, false);
}
#else
__device__ inline float dot2(h2 a, h2 b, float c) {
  return fmaf((float)a.x, (float)b.x, fmaf((float)a.y, (float)b.y, c));
}
#endif

// ---- workspace zeroing (single cheap kernel; pool+pcnt contiguous) --------
__global__ __launch_bounds__(256) void k_zero(int* __restrict__ bcur,
                                              int* __restrict__ gcur,
                                              float4* __restrict__ poolv) {
  const int t = blockIdx.x * 256 + threadIdx.x;
  poolv[t] = make_float4(0.f, 0.f, 0.f, 0.f);
  if (t < NBK) bcur[t] = 0;
  if (t < 64) gcur[t] = 0;
}

// ---- phase 1: bucket-bin edges (u32 = dloc<<17 | src), block-local runs ----
__global__ __launch_bounds__(256) void k_bin(const int* __restrict__ src,
                                             const int* __restrict__ dst,
                                             int* __restrict__ bcur,
                                             u32* __restrict__ ebuf) {
  __shared__ int d_s[CHUNK];          // 25 KB: dst chunk staged once
  __shared__ int bcnt[NBK], bpos[NBK];
  const int e0 = blockIdx.x * CHUNK;
  const int e1 = min(e0 + CHUNK, NE);
  for (int i = threadIdx.x; i < NBK; i += 256) bcnt[i] = 0;
  __syncthreads();
  for (int e = e0 + threadIdx.x; e < e1; e += 256) {
    const int d = dst[e];
    d_s[e - e0] = d;
    atomicAdd(&bcnt[d / BKN], 1);
  }
  __syncthreads();
  for (int i = threadIdx.x; i < NBK; i += 256) {
    const int c = bcnt[i];
    if (c) bpos[i] = i * CAP + atomicAdd(&bcur[i], c);
  }
  __syncthreads();
  for (int e = e0 + threadIdx.x; e < e1; e += 256) {
    const int d = d_s[e - e0];
    const int bk = d / BKN;
    const int pos = atomicAdd(&bpos[bk], 1);
    ebuf[pos] = ((u32)(d - bk * BKN) << 17) | (u32)src[e];
  }
}

// ---- phase 2: per-bucket CSR build, src-octant-ordered adjacency ----------
__global__ __launch_bounds__(256) void k_csr(const int* __restrict__ bcur,
                                             const u32* __restrict__ ebuf,
                                             int* __restrict__ row_ptr,
                                             int* __restrict__ cnt,
                                             float* __restrict__ dinv,
                                             int* __restrict__ csr_src) {
  __shared__ u32 eb_s[CAP];           // 16 KB
  __shared__ int deg[256], sc[256], cur[256];
  const int bk = blockIdx.x;
  const int nlo = bk * BKN;
  if (nlo >= NN) return;
  const int nloc = min(BKN, NN - nlo);
  const int cntE = bcur[bk];
  const int t = threadIdx.x;
  for (int e = t; e < cntE; e += 256) eb_s[e] = ebuf[(size_t)bk * CAP + e];
  deg[t] = 0;
  __syncthreads();
  for (int e = t; e < cntE; e += 256) atomicAdd(&deg[eb_s[e] >> 17], 1);
  __syncthreads();
  sc[t] = deg[t];
  __syncthreads();
  for (int off = 1; off < 256; off <<= 1) {
    const int add = (t >= off) ? sc[t - off] : 0;
    __syncthreads();
    sc[t] += add;
    __syncthreads();
  }
  const int excl = bk * CAP + sc[t] - deg[t];
  if (t < nloc) {
    row_ptr[nlo + t] = excl;
    cnt[nlo + t] = deg[t];
    dinv[nlo + t] = 1.0f / sqrtf((float)deg[t] + 1.0f);
  }
  cur[t] = excl;
  __syncthreads();
  for (int oct = 0; oct < 8; ++oct) {
    for (int e = t; e < cntE; e += 256) {
      const u32 ent = eb_s[e];
      const int s = (int)(ent & 0x1ffffu);
      if (((s >> 14) & 7) == oct) {
        const int pos = atomicAdd(&cur[ent >> 17], 1);
        csr_src[pos] = s << 4;  // pre-scaled (u64 units)
      }
    }
    __syncthreads();
  }
  for (int e = cntE + t; e < min(cntE + 64, CAP); e += 256)
    csr_src[bk * CAP + e] = 0;
}

// ---- degree counting sort: order[] groups nodes of equal/adjacent degree ---
__global__ __launch_bounds__(256) void k_obin(const int* __restrict__ cnt,
                                              int* __restrict__ gcur) {
  __shared__ int lh[64];
  const int t = threadIdx.x;
  if (t < 64) lh[t] = 0;
  __syncthreads();
  const int n = blockIdx.x * 256 + t;
  if (n < NN) atomicAdd(&lh[min(cnt[n], 63)], 1);
  __syncthreads();
  if (t < 64 && lh[t]) atomicAdd(&gcur[t], lh[t]);
}

__global__ __launch_bounds__(64) void k_oscan(int* __restrict__ gcur) {
  __shared__ int sh[64];
  const int t = threadIdx.x;
  const int v = gcur[t];
  sh[t] = v;
  __syncthreads();
  for (int off = 1; off < 64; off <<= 1) {
    const int a = (t >= off) ? sh[t - off] : 0;
    __syncthreads();
    sh[t] += a;
    __syncthreads();
  }
  gcur[t] = sh[t] - v;  // exclusive offset -> running cursor
}

__global__ __launch_bounds__(256) void k_oscat(const int* __restrict__ cnt,
                                               int* __restrict__ gcur,
                                               int* __restrict__ order) {
  __shared__ int lh[64], lo[64];
  const int t = threadIdx.x;
  if (t < 64) lh[t] = 0;
  __syncthreads();
  const int n = blockIdx.x * 256 + t;
  int bin = 0, loc = 0;
  if (n < NN) {
    bin = min(cnt[n], 63);
    loc = atomicAdd(&lh[bin], 1);
  }
  __syncthreads();
  if (t < 64 && lh[t]) lo[t] = atomicAdd(&gcur[t], lh[t]);
  __syncthreads();
  if (n < NN) order[lo[bin] + loc] = n;
}

// ---- node GEMM: fp16 + v_dot2_f32_f16, fp32 accumulate, 64-row tiles ------
// Block 256 threads = tile 64 rows x 64 cols; thread = 2 rows x 8 cols.
// IN16: input is packed-fp16 activations (h16) -> staging is a pure uint4
// copy (values bit-identical to the old fp32->fp16 conversion path).
// A: TXOR swizzle; B: WIDX bank-quad offset. SK: skip fp16 -> outS16.
// NOTE: inner-K loop must stay "#pragma unroll 2" (R20: full unroll spilled).
#define TXOR(row) ((((row) >> 3) & 3) << 2)
#define WIDX(c, kp) ((c) * WS + (((c) >> 3) << 2) + (kp))
template <int CI, bool SK, bool IN16>
__global__ __launch_bounds__(256) void k_gemm(const void* __restrict__ in,
                                              const float* __restrict__ W,
                                              const float* __restrict__ Ws,
                                              const float* __restrict__ bs,
                                              const float* __restrict__ dinv,
                                              u32* __restrict__ out16,
                                              u32* __restrict__ outS16) {
  constexpr int KP = CI / 2;          // half2 per row
  constexpr int RS = KP + 4;          // tin2 row stride
  constexpr int WS = KP + 4;          // wt2 col stride (+ per-col quad offset)
  __shared__ h2 tin2[64 * RS];
  __shared__ h2 wt2[64 * WS + 32];
  __shared__ h2 wsl2[SK ? 64 * WS + 32 : 1];
  union U2 { uint2 u; h2 h[2]; };
  union U4 { uint4 u; h2 h[4]; };

  const int row0 = blockIdx.x * 64;
  // stage weights (transposed, fp16)
  for (int i = threadIdx.x; i < 64 * KP; i += 256) {
    const int c = i & 63;
    const int kp = i >> 6;
    wt2[WIDX(c, kp)] = h2{(_Float16)W[(2 * kp) * 64 + c],
                          (_Float16)W[(2 * kp + 1) * 64 + c]};
    if (SK)
      wsl2[WIDX(c, kp)] = h2{(_Float16)Ws[(2 * kp) * 64 + c],
                             (_Float16)Ws[(2 * kp + 1) * 64 + c]};
  }
  // stage input tile
  if (IN16) {
    const u32* in16 = (const u32*)in;
#pragma unroll
    for (int s = 0; s < (64 * KP / 4) / 256; ++s) {
      const int idx = (s * 256 + threadIdx.x) * 4;  // h2 units, quad-aligned
      const int r = idx / KP;
      const int kpq = idx % KP;
      const int rowc = min(row0 + r, NN - 1);
      const uint4 v = *(const uint4*)&in16[(size_t)rowc * KP + kpq];
      *(uint4*)&tin2[r * RS + (kpq ^ TXOR(r))] = v;
    }
  } else {
    const float* inf = (const float*)in;
    for (int s = 0; s < (64 * CI) / 1024; ++s) {
      const int idx = (s * 256 + threadIdx.x) * 4;
      const int r = idx / CI;
      const int k = idx % CI;
      const int rowc = min(row0 + r, NN - 1);
      const float4 v = *(const float4*)(inf + (size_t)rowc * CI + k);
      U2 a;
      a.h[0] = h2{(_Float16)v.x, (_Float16)v.y};
      a.h[1] = h2{(_Float16)v.z, (_Float16)v.w};
      const int kp = (k >> 1) ^ TXOR(r);
      *(uint2*)&tin2[r * RS + kp] = a.u;
    }
  }
  __syncthreads();

  const int rg = threadIdx.x >> 3;  // 0..31: 2-row group
  const int cg = threadIdx.x & 7;   // 0..7 : 8-col group
  float acc[2][8];
  float sacc[SK ? 2 : 1][8];
#pragma unroll
  for (int i = 0; i < 2; ++i)
#pragma unroll
    for (int j = 0; j < 8; ++j) acc[i][j] = 0.0f;
  if (SK) {
#pragma unroll
    for (int i = 0; i < 2; ++i)
#pragma unroll
      for (int j = 0; j < 8; ++j) sacc[i][j] = bs[cg * 8 + j];
  }

  const int tx = TXOR(rg * 2);  // same for the thread's 2 rows (2rg even)
#pragma unroll 2
  for (int kq = 0; kq < KP / 4; ++kq) {
    U4 A[2], B[8];
#pragma unroll
    for (int r = 0; r < 2; ++r)
      A[r].u = *(const uint4*)&tin2[(rg * 2 + r) * RS + ((kq * 4) ^ tx)];
#pragma unroll
    for (int c = 0; c < 8; ++c)
      B[c].u = *(const uint4*)&wt2[WIDX(cg * 8 + c, kq * 4)];
#pragma unroll
    for (int r = 0; r < 2; ++r)
#pragma unroll
      for (int c = 0; c < 8; ++c)
#pragma unroll
        for (int q = 0; q < 4; ++q)
          acc[r][c] = dot2(A[r].h[q], B[c].h[q], acc[r][c]);
    if (SK) {
      U4 C[8];
#pragma unroll
      for (int c = 0; c < 8; ++c)
        C[c].u = *(const uint4*)&wsl2[WIDX(cg * 8 + c, kq * 4)];
#pragma unroll
      for (int r = 0; r < 2; ++r)
#pragma unroll
        for (int c = 0; c < 8; ++c)
#pragma unroll
          for (int q = 0; q < 4; ++q)
            sacc[r][c] = dot2(A[r].h[q], C[c].h[q], sacc[r][c]);
    }
  }

#pragma unroll
  for (int i = 0; i < 2; ++i) {
    const int row = row0 + rg * 2 + i;
    if (row < NN) {
      const float dv = dinv[row];
      u32 o[4];
#pragma unroll
      for (int j = 0; j < 4; ++j)
        o[j] = packh2(acc[i][2 * j] * dv, acc[i][2 * j + 1] * dv);
      *(uint4*)&out16[(size_t)row * 32 + cg * 4] =
          make_uint4(o[0], o[1], o[2], o[3]);
      if (SK) {
        u32 so[4];
#pragma unroll
        for (int j = 0; j < 4; ++j)
          so[j] = packh2(sacc[i][2 * j], sacc[i][2 * j + 1]);
        *(uint4*)&outS16[(size_t)row * 32 + cg * 4] =
            make_uint4(so[0], so[1], so[2], so[3]);
      }
    }
  }
}

// ------- CSR aggregation + finalize (fp16 gather, 2 quads = 8 nodes/wave) ---
// Output h16 is PACKED FP16 (the gemm staging rounded to fp16 anyway, so
// downstream gemm inputs are bit-identical; only pool path sees rounding).
template <bool ADD_S>
__global__ __launch_bounds__(256) void k_agg(const u32* __restrict__ hw16,
                                             const u32* __restrict__ hs16,
                                             const int* __restrict__ csr_src,
                                             const int* __restrict__ row_ptr,
                                             const int* __restrict__ cnt,
                                             const float* __restrict__ dinv,
                                             const float* __restrict__ bias,
                                             const int* __restrict__ order,
                                             u32* __restrict__ h16) {
  const int lane = threadIdx.x & 63;
  const int grp  = lane >> 4;        // node within quad
  const int cl   = lane & 15;        // col-quad index (4 fp16 = 8 B)
  const int wv   = threadIdx.x >> 6;
  const int gid  = 12499 - (blockIdx.x * 4 + wv);  // high-degree first
  const int nA = order[(gid * 2) * 4 + grp];
  const int nB = order[(gid * 2 + 1) * 4 + grp];
  const int begA = row_ptr[nA], degA = cnt[nA];
  const int begB = row_ptr[nB], degB = cnt[nB];
  int d1 = max(degA, degB);
  d1 = max(d1, __shfl_xor(d1, 16));
  const int dmax = max(d1, __shfl_xor(d1, 32));
  const u64* hw64 = (const u64*)hw16;
  const int gbase = grp << 4;
  float4 accA = make_float4(0.f, 0.f, 0.f, 0.f);
  float4 accB = make_float4(0.f, 0.f, 0.f, 0.f);

#define GATH(dst, idxv, K0, NK)                                               \
  _Pragma("unroll") for (int k = 0; k < NK; ++k) {                            \
    const int p = __shfl(idxv, gbase + (K0) + k);                             \
    dst[k] = *(const uint2*)&hw64[(size_t)(p + cl)];                          \
  }
#define ACC(uv, accv, deg, K0, NK)                                            \
  _Pragma("unroll") for (int k = 0; k < NK; ++k) {                            \
    const float m = ((i + (K0) + k) < (deg)) ? 1.0f : 0.0f;                   \
    const float2 f0 = unpackh2(uv[k].x);                                      \
    const float2 f1 = unpackh2(uv[k].y);                                      \
    accv.x = fmaf(f0.x, m, accv.x);                                           \
    accv.y = fmaf(f0.y, m, accv.y);                                           \
    accv.z = fmaf(f1.x, m, accv.z);                                           \
    accv.w = fmaf(f1.y, m, accv.w);                                           \
  }

  int i = 0;
  while (i + 16 <= dmax) {
    const int ivA = __builtin_nontemporal_load(&csr_src[begA + i + cl]);
    const int ivB = __builtin_nontemporal_load(&csr_src[begB + i + cl]);
    uint2 a0[8], b0[8], a1[8], b1[8];
    GATH(a0, ivA, 0, 8)
    GATH(b0, ivB, 0, 8)
    ACC(a0, accA, degA, 0, 8)
    GATH(a1, ivA, 8, 8)
    ACC(b0, accB, degB, 0, 8)
    GATH(b1, ivB, 8, 8)
    ACC(a1, accA, degA, 8, 8)
    ACC(b1, accB, degB, 8, 8)
    i += 16;
  }
  if (i < dmax) {
    const int ivA = __builtin_nontemporal_load(&csr_src[begA + i + cl]);
    const int ivB = __builtin_nontemporal_load(&csr_src[begB + i + cl]);
    const int rem = dmax - i;  // wave-uniform, 1..15
    int k0 = 0;
    if (rem & 8) {
      uint2 a[8], b[8];
      GATH(a, ivA, k0, 8) GATH(b, ivB, k0, 8)
      ACC(a, accA, degA, k0, 8) ACC(b, accB, degB, k0, 8)
      k0 += 8;
    }
    if (rem & 4) {
      uint2 a[4], b[4];
      GATH(a, ivA, k0, 4) GATH(b, ivB, k0, 4)
      ACC(a, accA, degA, k0, 4) ACC(b, accB, degB, k0, 4)
      k0 += 4;
    }
    if (rem & 2) {
      uint2 a[2], b[2];
      GATH(a, ivA, k0, 2) GATH(b, ivB, k0, 2)
      ACC(a, accA, degA, k0, 2) ACC(b, accB, degB, k0, 2)
      k0 += 2;
    }
    if (rem & 1) {
      uint2 a[1], b[1];
      GATH(a, ivA, k0, 1) GATH(b, ivB, k0, 1)
      ACC(a, accA, degA, k0, 1) ACC(b, accB, degB, k0, 1)
    }
  }
#undef GATH
#undef ACC

#define FINAL(n, accv)                                                        \
  {                                                                           \
    const uint2 sv = *(const uint2*)&hw64[(size_t)(n) * 16 + cl];             \
    const float2 s0 = unpackh2(sv.x);                                         \
    const float2 s1 = unpackh2(sv.y);                                         \
    const float dv = dinv[n];                                                 \
    const float4 brc = *(const float4*)&bias[cl * 4];                         \
    float4 r;                                                                 \
    r.x = fmaxf((accv.x + s0.x) * dv + brc.x, 0.0f);                          \
    r.y = fmaxf((accv.y + s0.y) * dv + brc.y, 0.0f);                          \
    r.z = fmaxf((accv.z + s1.x) * dv + brc.z, 0.0f);                          \
    r.w = fmaxf((accv.w + s1.y) * dv + brc.w, 0.0f);                          \
    if (ADD_S) {                                                              \
      const uint2 sv2 = *(const uint2*)&hs16[(size_t)(n) * 32 + cl * 2];      \
      const float2 q0 = unpackh2(sv2.x);                                      \
      const float2 q1 = unpackh2(sv2.y);                                      \
      r.x += q0.x; r.y += q0.y; r.z += q1.x; r.w += q1.y;                     \
    }                                                                         \
    *(uint2*)&h16[(size_t)(n) * 32 + cl * 2] =                                \
        make_uint2(packh2(r.x, r.y), packh2(r.z, r.w));                       \
  }
  FINAL(nA, accA)
  FINAL(nB, accB)
#undef FINAL
}

// -------- mean-pool (fp16 input): b SORTED -> run-length accumulate --------
__global__ __launch_bounds__(256) void k_pool(const u32* __restrict__ h16,
                                              const int* __restrict__ b,
                                              float* __restrict__ pool,
                                              float* __restrict__ cnt) {
  const int col = threadIdx.x & 63;
  const int wv  = threadIdx.x >> 6;
  const int node0 = (blockIdx.x * 4 + wv) * 64;
  if (node0 >= NN) return;
  const int node1 = min(node0 + 64, NN);
  int gcur = b[node0];
  float acc = 0.f;
  float run = 0.f;
  for (int n = node0; n < node1; ++n) {
    const int g = b[n];  // wave-uniform broadcast load
    if (g != gcur) {
      atomicAdd(&pool[(size_t)gcur * 64 + col], acc);
      if (col == 0) atomicAdd(&cnt[gcur], run);
      gcur = g; acc = 0.f; run = 0.f;
    }
    const float2 f = unpackh2(h16[(size_t)n * 32 + (col >> 1)]);
    acc += (col & 1) ? f.y : f.x;
    run += 1.f;
  }
  atomicAdd(&pool[(size_t)gcur * 64 + col], acc);
  if (col == 0) atomicAdd(&cnt[gcur], run);
}

// ---------------- MLP head ----------------
__global__ __launch_bounds__(64) void k_head(const float* __restrict__ pool,
                                             const float* __restrict__ cnt,
                                             const float* __restrict__ lin1W,
                                             const float* __restrict__ lin1b,
                                             const float* __restrict__ lin2W,
                                             const float* __restrict__ lin2b,
                                             float* __restrict__ out) {
  const int g = blockIdx.x;
  const int lane = threadIdx.x;
  const float c = fmaxf(cnt[g], 1.0f);
  float r = 0.f;
  if (lane < 32) {
    float s = lin1b[lane];
    const float* p = pool + (size_t)g * 64;
#pragma unroll 8
    for (int ci = 0; ci < 64; ++ci) s = fmaf(p[ci] / c, lin1W[ci * 32 + lane], s);
    r = fmaxf(s, 0.0f) * lin2W[lane];
  }
  for (int off = 32; off > 0; off >>= 1) r += __shfl_down(r, off, 64);
  if (lane == 0) out[g] = r + lin2b[0];
}

extern "C" void kernel_launch(void* const* d_in, const int* in_sizes, int n_in,
                              void* d_out, int out_size, void* d_ws, size_t ws_size,
                              hipStream_t stream) {
  const float* x     = (const float*)d_in[0];
  const int*   src   = (const int*)d_in[1];            // e_idx[0]
  const int*   dst   = ((const int*)d_in[1]) + NE;     // e_idx[1]
  const int*   b     = (const int*)d_in[2];
  const float* w0    = (const float*)d_in[3];
  const float* b0    = (const float*)d_in[4];
  const float* convW = (const float*)d_in[5];
  const float* convB = (const float*)d_in[6];
  const float* skipW = (const float*)d_in[7];
  const float* skipB = (const float*)d_in[8];
  const float* lin1W = (const float*)d_in[9];
  const float* lin1b = (const float*)d_in[10];
  const float* lin2W = (const float*)d_in[11];
  const float* lin2b = (const float*)d_in[12];
  float* out = (float*)d_out;

  // ---- workspace layout ----
  char* w = (char*)d_ws;
  const size_t NPAD = 102400;
  int*   cnt     = (int*)w;                  w += NPAD * 4;
  float* dinv    = (float*)w;                w += NPAD * 4;
  int*   row_ptr = (int*)w;                  w += NPAD * 4;
  int*   order   = (int*)w;                  w += NPAD * 4;
  int*   bcur    = (int*)w;                  w += 1024 * 4;
  int*   gcur    = (int*)w;                  w += 1024 * 4;
  int*   csr_src = (int*)w;                  w += (size_t)NBK * CAP * 4 + 4096;
  char*  big     = w;                        w += (size_t)NN * 32 * 4;     // 12.8MB
  u32*   hs16    = (u32*)w;                  w += (size_t)NN * 32 * 4;     // 12.8MB
  u32*   h16     = (u32*)w;                  w += (size_t)NN * 32 * 4;     // 12.8MB
  float* pool    = (float*)w;                w += (size_t)NG * 64 * 4;
  float* pcnt    = (float*)w;                w += (size_t)NG * 4;
  // ebuf (6.4MB, dead after k_csr) and hw16 (12.8MB) share `big`.
  u32* ebuf = (u32*)big;
  u32* hw16 = (u32*)big;

  // ---- zero workspace counters + pool (one kernel; pool+pcnt contiguous) ---
  k_zero<<<260, 256, 0, stream>>>(bcur, gcur, (float4*)pool);

  // ---- CSR build: bucket sort, octant-ordered, pre-scaled (once/launch) ----
  k_bin<<<NBLK_BIN, 256, 0, stream>>>(src, dst, bcur, ebuf);
  k_csr<<<NBK, 256, 0, stream>>>(bcur, ebuf, row_ptr, cnt, dinv, csr_src);
  // degree counting sort -> order[]
  const int OB = (NN + 255) / 256;  // 391
  k_obin<<<OB, 256, 0, stream>>>(cnt, gcur);
  k_oscan<<<1, 64, 0, stream>>>(gcur);
  k_oscat<<<OB, 256, 0, stream>>>(cnt, gcur, order);

  const int GT = (NN + 63) / 64;  // 1563 tiles

  // ---- layer 0 ----
  k_gemm<NF, false, false><<<GT, 256, 0, stream>>>(x, w0, nullptr, nullptr,
                                                   dinv, hw16, nullptr);
  k_agg<false><<<3125, 256, 0, stream>>>(hw16, nullptr, csr_src, row_ptr, cnt,
                                         dinv, b0, order, h16);
  // ---- layers 1..2 ----
  for (int i = 0; i < 2; ++i) {
    k_gemm<H, true, true><<<GT, 256, 0, stream>>>(h16, convW + (size_t)i * H * H,
                                                  skipW + (size_t)i * H * H,
                                                  skipB + (size_t)i * H, dinv,
                                                  hw16, hs16);
    k_agg<true><<<3125, 256, 0, stream>>>(hw16, hs16, csr_src, row_ptr, cnt,
                                          dinv, convB + (size_t)i * H, order, h16);
  }

  // ---- mean pool + head ----
  k_pool<<<(NN / 256) + 1, 256, 0, stream>>>(h16, b, pool, pcnt);
  k_head<<<NG, 64, 0, stream>>>(pool, pcnt, lin1W, lin1b, lin2W, lin2b, out);
}